// Round 5
// baseline (281.684 us; speedup 1.0000x reference)
//
#include <hip/hip_runtime.h>

typedef unsigned short u16;
typedef unsigned int u32;
typedef __attribute__((ext_vector_type(8))) short short8v;   // 8 x bf16 (raw bits)
typedef __attribute__((ext_vector_type(4))) float f32x4;

#define DD 768
#define PP 1024
#define NTOK 4096
#define ASN 520   // act row stride (u16): 520*2 B = 16B-aligned rows; stride ≡ 4 mod 32 dwords
                  // -> phase-A uint2 stores ~4-way, phase-B b128 reads at the 8-cyc floor

__device__ __forceinline__ u16 f2bf(float f) {
  u32 u = __builtin_bit_cast(u32, f);
  u += 0x7fffu + ((u >> 16) & 1u);
  return (u16)(u >> 16);
}
__device__ __forceinline__ float b2f(u16 v) {
  return __builtin_bit_cast(float, (u32)v << 16);
}
// extract element j of a bf16x8 register as float (j compile-time after unroll)
__device__ __forceinline__ float ex8(const short8v& v, int j) {
  const u32 dw = ((const u32*)&v)[j >> 1];
  return __builtin_bit_cast(float, (j & 1) ? (dw & 0xffff0000u) : (dw << 16));
}

// ---------------- weight f32 -> bf16 (3 matrices of 589824) ----------------
__global__ __launch_bounds__(256) void cvt_w(const float* __restrict__ a, u16* __restrict__ oa,
                                             const float* __restrict__ b, u16* __restrict__ ob,
                                             const float* __restrict__ c, u16* __restrict__ oc) {
  const int i = blockIdx.x * 256 + threadIdx.x;
  const int m = blockIdx.y;
  const float* s = (m == 0) ? a : (m == 1) ? b : c;
  u16* d = (m == 0) ? oa : (m == 1) ? ob : oc;
  d[i] = f2bf(s[i]);
}

// ---------------- xdown weight -> bf16, padded 48x768 -> 64x768 (rows 48+ zero) ----------------
__global__ __launch_bounds__(256) void cvt_xd(const float* __restrict__ w, u16* __restrict__ o) {
  const int i = blockIdx.x * 256 + threadIdx.x;   // 64*768 = 49152
  const int r = i / DD;
  o[i] = (r < 48) ? f2bf(w[i]) : (u16)0;
}

// ---------------- gather scan weights: wB[c][32 rows][64 k] bf16, zero-padded ----------------
// row = type*4 + k ; type in {Gl,Gm,Gr,L,U,D}; rows 24..31 zero, cols 48..63 zero
__global__ __launch_bounds__(256) void wcat_k(const float* __restrict__ wup,
                                              const float* __restrict__ lup,
                                              const float* __restrict__ uup,
                                              const float* __restrict__ dco,
                                              u16* __restrict__ wB) {
  const int c = blockIdx.x;
  const int t = threadIdx.x;
  u16* dst = wB + (size_t)c * 2048;
  for (int i = t; i < 2048; i += 256) {
    const int row = i >> 6, s = i & 63;
    u16 v = 0;
    if (row < 24 && s < 48) {
      const int k = row & 3, type = row >> 2;
      const int ch = k * DD + c;
      const float* src;
      if (type < 3) src = wup + ((size_t)(type * 3072 + ch)) * 48;
      else if (type == 3) src = lup + (size_t)ch * 48;
      else if (type == 4) src = uup + (size_t)ch * 48;
      else src = dco + (size_t)ch * 48;
      v = f2bf(src[s]);
    }
    dst[i] = v;
  }
}

// ---------------- LayerNorm + shortcut copy ----------------
__global__ __launch_bounds__(256) void ln_k(const float* __restrict__ x,
                                            const float* __restrict__ gw, const float* __restrict__ gb,
                                            u16* __restrict__ lnout, float* __restrict__ shortcut) {
  const int tok = blockIdx.x;
  const int t = threadIdx.x;
  const float* xr = x + (size_t)tok * DD;
  float v0 = xr[t], v1 = xr[t + 256], v2 = xr[t + 512];
  float s = v0 + v1 + v2;
  float q = v0 * v0 + v1 * v1 + v2 * v2;
#pragma unroll
  for (int off = 32; off > 0; off >>= 1) {
    s += __shfl_down(s, off, 64);
    q += __shfl_down(q, off, 64);
  }
  __shared__ float ss[4], qs[4];
  const int wid = t >> 6, lane = t & 63;
  if (lane == 0) { ss[wid] = s; qs[wid] = q; }
  __syncthreads();
  const float st = ss[0] + ss[1] + ss[2] + ss[3];
  const float qt = qs[0] + qs[1] + qs[2] + qs[3];
  const float mu = st * (1.f / 768.f);
  const float var = qt * (1.f / 768.f) - mu * mu;
  const float rstd = rsqrtf(var + 1e-5f);
  float* sc = shortcut + (size_t)tok * DD;
  u16* lo = lnout + (size_t)tok * DD;
  sc[t] = v0; sc[t + 256] = v1; sc[t + 512] = v2;
  lo[t]       = f2bf((v0 - mu) * rstd * gw[t] + gb[t]);
  lo[t + 256] = f2bf((v1 - mu) * rstd * gw[t + 256] + gb[t + 256]);
  lo[t + 512] = f2bf((v2 - mu) * rstd * gw[t + 512] + gb[t + 512]);
}

// ---------------- bf16 MFMA GEMM: out[o,pg] = sum_c A[o,c]*Bt[pg,c] ----------------
// A: [M x 768] bf16 row-major;  Bt: 4096x768 bf16 token-major
// mode 0: store f32 channel-major out[(b*768+o)*1024 + p]
// mode 1: store f32 token-major   out[pg*768 + o]
// mode 2: store bf16 to xpA[(b*1024 + i)*64 + o], i = (w>>4)*512 + h*16 + (w&15)  (h-major!)
__global__ __launch_bounds__(256) void gemm_bf16(const u16* __restrict__ A,
                                                 const u16* __restrict__ Bt,
                                                 float* __restrict__ out, const int mode) {
  __shared__ u16 Al[64][40];
  __shared__ u16 Bl[128][40];
  const int t = threadIdx.x;
  const int ntile = blockIdx.x * 128;
  const int mtile = blockIdx.y * 64;
  const int wid = t >> 6, lane = t & 63;
  const int m0 = (wid & 1) * 32, n0 = (wid >> 1) * 64;
  const int l15 = lane & 15, quad = lane >> 4;
  f32x4 acc[2][4];
#pragma unroll
  for (int mi = 0; mi < 2; ++mi)
#pragma unroll
    for (int ni = 0; ni < 4; ++ni) acc[mi][ni] = (f32x4){0.f, 0.f, 0.f, 0.f};
  const int ra = t >> 2, sa = t & 3;
  const int rb = t >> 1, hb = t & 1;
  const u16* ag = A + (size_t)(mtile + ra) * DD + sa * 8;
  const u16* bg = Bt + (size_t)(ntile + rb) * DD + hb * 16;
  for (int k0 = 0; k0 < DD; k0 += 32) {
    const uint4 av = *reinterpret_cast<const uint4*>(ag + k0);
    const uint4 bv0 = *reinterpret_cast<const uint4*>(bg + k0);
    const uint4 bv1 = *reinterpret_cast<const uint4*>(bg + k0 + 8);
    __syncthreads();
    *reinterpret_cast<uint4*>(&Al[ra][sa * 8]) = av;
    *reinterpret_cast<uint4*>(&Bl[rb][hb * 16]) = bv0;
    *reinterpret_cast<uint4*>(&Bl[rb][hb * 16 + 8]) = bv1;
    __syncthreads();
    short8v af[2];
#pragma unroll
    for (int mi = 0; mi < 2; ++mi)
      af[mi] = *reinterpret_cast<const short8v*>(&Al[m0 + mi * 16 + l15][quad * 8]);
    short8v bfr[4];
#pragma unroll
    for (int ni = 0; ni < 4; ++ni)
      bfr[ni] = *reinterpret_cast<const short8v*>(&Bl[n0 + ni * 16 + l15][quad * 8]);
#pragma unroll
    for (int mi = 0; mi < 2; ++mi)
#pragma unroll
      for (int ni = 0; ni < 4; ++ni)
        acc[mi][ni] = __builtin_amdgcn_mfma_f32_16x16x32_bf16(af[mi], bfr[ni], acc[mi][ni], 0, 0, 0);
  }
#pragma unroll
  for (int mi = 0; mi < 2; ++mi) {
#pragma unroll
    for (int ni = 0; ni < 4; ++ni) {
      const int ob = mtile + m0 + mi * 16 + quad * 4;
      const int pg = ntile + n0 + ni * 16 + l15;
      if (mode == 0) {
        const int bb = pg >> 10, pq = pg & 1023;
#pragma unroll
        for (int r = 0; r < 4; ++r)
          out[((size_t)(bb * DD + ob + r)) * PP + pq] = acc[mi][ni][r];
      } else if (mode == 1) {
        *reinterpret_cast<f32x4*>(out + (size_t)pg * DD + ob) = acc[mi][ni];
      } else {
        const int bb = pg >> 10, pq = pg & 1023;
        const int q = ((pq & 31) >> 4) * 512 + (pq >> 5) * 16 + (pq & 15);
        u16* dst = (u16*)out + ((size_t)(bb * 1024 + q)) * 64 + ob;
        const u32 lo = (u32)f2bf(acc[mi][ni][0]) | ((u32)f2bf(acc[mi][ni][1]) << 16);
        const u32 hi = (u32)f2bf(acc[mi][ni][2]) | ((u32)f2bf(acc[mi][ni][3]) << 16);
        *reinterpret_cast<uint2*>(dst) = make_uint2(lo, hi);
      }
    }
  }
}

// ---------------- depthwise 7x7 + bias, f32 -> f32 ----------------
__global__ __launch_bounds__(256) void dwconv7_k(const float* __restrict__ x,
                                                 const float* __restrict__ wgt,
                                                 const float* __restrict__ bias,
                                                 float* __restrict__ y) {
  const int bc = blockIdx.x;
  const int c = bc % DD;
  __shared__ float tile[38 * 38];
  __shared__ float wl[49];
  __shared__ float bsh[1];
  const int t = threadIdx.x;
  for (int i = t; i < 38 * 38; i += 256) tile[i] = 0.f;
  __syncthreads();
  const float* xr = x + (size_t)bc * PP;
  for (int i = t; i < 1024; i += 256) tile[((i >> 5) + 3) * 38 + (i & 31) + 3] = xr[i];
  if (t < 49) wl[t] = wgt[c * 49 + t];
  if (t == 0) bsh[0] = bias[c];
  __syncthreads();
  float* yo = y + (size_t)bc * PP;
  for (int i = t; i < 1024; i += 256) {
    const int h = i >> 5, w = i & 31;
    float acc = bsh[0];
#pragma unroll
    for (int kh = 0; kh < 7; ++kh)
#pragma unroll
      for (int kw = 0; kw < 7; ++kw)
        acc = fmaf(wl[kh * 7 + kw], tile[(h + kh) * 38 + (w + kw)], acc);
    yo[i] = acc;
  }
}

// ---------------- depthwise 3x3 (no bias) + x*relu(x), f32 -> bf16 ----------------
__global__ __launch_bounds__(256) void dwconv3_k(const float* __restrict__ x,
                                                 const float* __restrict__ wgt,
                                                 u16* __restrict__ y) {
  const int bc = blockIdx.x;
  const int c = bc % DD;
  __shared__ float tile[34 * 34];
  __shared__ float wl[9];
  const int t = threadIdx.x;
  for (int i = t; i < 34 * 34; i += 256) tile[i] = 0.f;
  __syncthreads();
  const float* xr = x + (size_t)bc * PP;
  for (int i = t; i < 1024; i += 256) tile[((i >> 5) + 1) * 34 + (i & 31) + 1] = xr[i];
  if (t < 9) wl[t] = wgt[c * 9 + t];
  __syncthreads();
  u16* yo = y + (size_t)bc * PP;
  for (int i = t; i < 1024; i += 256) {
    const int h = i >> 5, w = i & 31;
    float acc = 0.f;
#pragma unroll
    for (int kh = 0; kh < 3; ++kh)
#pragma unroll
      for (int kw = 0; kw < 3; ++kw)
        acc = fmaf(wl[kh * 3 + kw], tile[(h + kh) * 34 + (w + kw)], acc);
    const float r = acc > 0.f ? acc * acc : 0.f;
    yo[i] = f2bf(r);
  }
}

// ---------------- fused MFMA projections + 4-direction chunked scan + recombine ----------------
// grid = 6144: blockIdx.x = bc*2 + half; half selects w in [half*16, half*16+16).
// xpA rows are h-major within each half: i_local = h*16 + (w&15)  -> MFMA D rows land so that
// act[coef][i_local] has the 8 j-values of a (h, chunk) contiguous => ONE ds_read_b128 per coef.
// Phase B: wave wid = (ncl<<1)|dpair; lane = d*32 + h; lane owns direction k = dpair*2+d.
__global__ __launch_bounds__(256, 4) void scan_k(const float* __restrict__ y2,
                                                 const u16* __restrict__ xpA,
                                                 const u16* __restrict__ wB,
                                                 const float* __restrict__ mwp,
                                                 u16* __restrict__ out1) {
  const int bid = blockIdx.x;
  const int bc = bid >> 1;
  const int half = bid & 1;
  const int b = bc / DD;
  const int c = bc - b * DD;
  __shared__ u16 act[24 * ASN];       // 24,960 B
  __shared__ float plane[32][33];     //  4,224 B  plane[h][w] = x(h,w)
  __shared__ float planeT[32][33];    //  4,224 B  planeT[h][w] = x(w,h)
  __shared__ float outp[2][16][33];   //  4,224 B
  const int t = threadIdx.x;
  const int wid = t >> 6, lane = t & 63, l15 = lane & 15, quad = lane >> 4;
  {
    const float* yp = y2 + (size_t)bc * PP;
    for (int i = t; i < 1024; i += 256) {
      const float v = yp[i];
      const int hh = i >> 5, ww = i & 31;
      plane[hh][ww] = v;
      planeT[ww][hh] = v;
    }
  }
  // ---- phase A: projections via MFMA (512 i-rows, 128 per wave) ----
  {
    const u16* wc = wB + (size_t)c * 2048;
    short8v bw[2][2];
#pragma unroll
    for (int nt = 0; nt < 2; ++nt)
#pragma unroll
      for (int ks = 0; ks < 2; ++ks)
        bw[nt][ks] = *reinterpret_cast<const short8v*>(wc + (nt * 16 + l15) * 64 + ks * 32 + quad * 8);
    const u16* ab = xpA + ((size_t)(b * 1024 + half * 512 + wid * 128)) * 64;
#pragma unroll 4
    for (int mt = 0; mt < 8; ++mt) {
      const u16* ar = ab + (mt * 16 + l15) * 64 + quad * 8;
      const short8v a0 = *reinterpret_cast<const short8v*>(ar);
      const short8v a1 = *reinterpret_cast<const short8v*>(ar + 32);
      f32x4 acc0 = {0.f, 0.f, 0.f, 0.f}, acc1 = {0.f, 0.f, 0.f, 0.f};
      acc0 = __builtin_amdgcn_mfma_f32_16x16x32_bf16(a0, bw[0][0], acc0, 0, 0, 0);
      acc0 = __builtin_amdgcn_mfma_f32_16x16x32_bf16(a1, bw[0][1], acc0, 0, 0, 0);
      acc1 = __builtin_amdgcn_mfma_f32_16x16x32_bf16(a0, bw[1][0], acc1, 0, 0, 0);
      acc1 = __builtin_amdgcn_mfma_f32_16x16x32_bf16(a1, bw[1][1], acc1, 0, 0, 0);
      const int qb = wid * 128 + mt * 16 + quad * 4;   // D: i_local = quad*4+reg (within tile)
      const u32 lo0 = (u32)f2bf(acc0[0]) | ((u32)f2bf(acc0[1]) << 16);
      const u32 hi0 = (u32)f2bf(acc0[2]) | ((u32)f2bf(acc0[3]) << 16);
      *reinterpret_cast<uint2*>(&act[l15 * ASN + qb]) = make_uint2(lo0, hi0);
      if (l15 < 8) {
        const u32 lo1 = (u32)f2bf(acc1[0]) | ((u32)f2bf(acc1[1]) << 16);
        const u32 hi1 = (u32)f2bf(acc1[2]) | ((u32)f2bf(acc1[3]) << 16);
        *reinterpret_cast<uint2*>(&act[(16 + l15) * ASN + qb]) = make_uint2(lo1, hi1);
      }
    }
  }
  __syncthreads();
  // ---- phase B: chunked scan, one direction per lane, act streams in registers ----
  const int dpair = wid & 1;      // 0: dirs {0,1}, 1: dirs {2,3}   (wave-uniform)
  const int ncl = wid >> 1;       // local chunk 0/1
  const int d = lane >> 5;        // direction within pair
  const int h = lane & 31;
  const int k = dpair * 2 + d;
  const float mw = mwp[k];
  const int base16 = h * 16 + ncl * 8;            // u16 offset within an act row
  const short8v vGl = *reinterpret_cast<const short8v*>(&act[(0  + k) * ASN + base16]);
  const short8v vGm = *reinterpret_cast<const short8v*>(&act[(4  + k) * ASN + base16]);
  const short8v vGr = *reinterpret_cast<const short8v*>(&act[(8  + k) * ASN + base16]);
  const short8v vL  = *reinterpret_cast<const short8v*>(&act[(12 + k) * ASN + base16]);
  const short8v vU  = *reinterpret_cast<const short8v*>(&act[(16 + k) * ASN + base16]);
  const short8v vD  = *reinterpret_cast<const short8v*>(&act[(20 + k) * ASN + base16]);
  const float* prow = (d == 0) ? &plane[h][0] : &planeT[h][0];
  float H = 0.f;
#pragma unroll
  for (int j = 0; j < 8; ++j) {
    const int w = half * 16 + ncl * 8 + j;   // global chunk position
    const int wc_ = dpair ? (31 - w) : w;    // w-flip for dirs 2,3
    const float xv = prow[wc_];
    float gl = 1.f / (1.f + __expf(-ex8(vGl, j)));
    float gm = 1.f / (1.f + __expf(-ex8(vGm, j)));
    float gr = 1.f / (1.f + __expf(-ex8(vGr, j)));
    float s = (h == 0) ? (gm + gr) : ((h == 31) ? (gl + gm) : (gl + gm + gr));
    s = fmaxf(s, 1e-7f);
    const float inv = 1.f / s;
    gl *= inv; gm *= inv; gr *= inv;
    float up = __shfl(H, lane - 1, 64);
    float dn = __shfl(H, lane + 1, 64);
    if (h == 0) up = 0.f;
    if (h == 31) dn = 0.f;
    H = ex8(vL, j) * xv + gl * up + gm * H + gr * dn;
    float part = mw * (H * ex8(vU, j) + xv * ex8(vD, j));
    part += __shfl_xor(part, 32, 64);        // combine the direction pair
    if (d == 0) outp[dpair][ncl * 8 + j][h] = part;
  }
  __syncthreads();
  const int hh = t >> 3, wp = t & 7;
  const float v0 = outp[0][wp * 2][hh] + outp[1][wp * 2][hh];
  const float v1 = outp[0][wp * 2 + 1][hh] + outp[1][wp * 2 + 1][hh];
  const u32 pk = (u32)f2bf(v0) | ((u32)f2bf(v1) << 16);
  *reinterpret_cast<u32*>(out1 + (size_t)bc * PP + hh * 32 + half * 16 + wp * 2) = pk;
}

// ---------------- bf16 transpose: [b][c][p] -> [(b*1024+p)][c] ----------------
__global__ __launch_bounds__(256) void transpose_bf16(const u16* __restrict__ in,
                                                      u16* __restrict__ out) {
  __shared__ u16 tile[64][72];
  const int b = blockIdx.z;
  const int c0 = blockIdx.y * 64;
  const int p0 = blockIdx.x * 64;
  const int t = threadIdx.x;
  const int r = t >> 2, s2 = t & 3;
  const u16* src = in + ((size_t)(b * DD + c0 + r)) * PP + p0 + s2 * 16;
  *reinterpret_cast<uint4*>(&tile[r][s2 * 16]) = *reinterpret_cast<const uint4*>(src);
  *reinterpret_cast<uint4*>(&tile[r][s2 * 16 + 8]) = *reinterpret_cast<const uint4*>(src + 8);
  __syncthreads();
  const int pr = t >> 2, cs = t & 3;
  union { u16 u[16]; uint4 v[2]; } vals;
#pragma unroll
  for (int i = 0; i < 16; ++i) vals.u[i] = tile[cs * 16 + i][pr];
  u16* dst = out + ((size_t)(b * 1024 + p0 + pr)) * DD + c0 + cs * 16;
  reinterpret_cast<uint4*>(dst)[0] = vals.v[0];
  reinterpret_cast<uint4*>(dst)[1] = vals.v[1];
}

// ---------------- f32 [b][c][p] -> bf16 token-major [(b*1024+p)][c] ----------------
__global__ __launch_bounds__(256) void transpose_f2b(const float* __restrict__ in,
                                                     u16* __restrict__ out) {
  __shared__ u16 tile[64][72];
  const int b = blockIdx.z;
  const int c0 = blockIdx.y * 64;
  const int p0 = blockIdx.x * 64;
  const int t = threadIdx.x;
  const int r = t >> 2, s2 = t & 3;
  const float* src = in + ((size_t)(b * DD + c0 + r)) * PP + p0 + s2 * 16;
  u16* td = &tile[r][s2 * 16];
#pragma unroll
  for (int q = 0; q < 4; ++q) {
    const float4 v = reinterpret_cast<const float4*>(src)[q];
    td[q * 4 + 0] = f2bf(v.x); td[q * 4 + 1] = f2bf(v.y);
    td[q * 4 + 2] = f2bf(v.z); td[q * 4 + 3] = f2bf(v.w);
  }
  __syncthreads();
  const int pr = t >> 2, cs = t & 3;
  union { u16 u[16]; uint4 v[2]; } vals;
#pragma unroll
  for (int i = 0; i < 16; ++i) vals.u[i] = tile[cs * 16 + i][pr];
  u16* dst = out + ((size_t)(b * 1024 + p0 + pr)) * DD + c0 + cs * 16;
  reinterpret_cast<uint4*>(dst)[0] = vals.v[0];
  reinterpret_cast<uint4*>(dst)[1] = vals.v[1];
}

extern "C" void kernel_launch(void* const* d_in, const int* in_sizes, int n_in,
                              void* d_out, int out_size, void* d_ws, size_t ws_size,
                              hipStream_t stream) {
  const float* hs   = (const float*)d_in[0];
  const float* nw   = (const float*)d_in[1];
  const float* nb   = (const float*)d_in[2];
  const float* win  = (const float*)d_in[3];
  const float* c7w  = (const float*)d_in[4];
  const float* c7b  = (const float*)d_in[5];
  const float* xdw  = (const float*)d_in[6];
  const float* wupw = (const float*)d_in[7];
  const float* lupw = (const float*)d_in[8];
  const float* uupw = (const float*)d_in[9];
  const float* dcow = (const float*)d_in[10];
  const float* mww  = (const float*)d_in[11];
  const float* wout = (const float*)d_in[12];
  const float* odw  = (const float*)d_in[13];
  const float* wprj = (const float*)d_in[14];
  float* out0 = (float*)d_out;
  float* shortcut = out0 + (size_t)NTOK * DD;

  char* ws = (char*)d_ws;
  // Slots: A: ln_bf16 (ln..gemm1) then out1_t. C: y1 (gemm1..dw7), then {xpA,wB,wXdB} (..scan), then y3.
  // D: y2 (dw7..scan) then y4_t. F: y2t (transpose_f2b..xdown_gemm) then out1_bf16 then y4_bf16.
  u16* lnA    = (u16*)(ws + 0);           // 6,291,456 B
  u16* wInB   = (u16*)(ws + 6291456);     // 1,179,648 B
  u16* wOutB  = (u16*)(ws + 7471104);     // 1,179,648 B
  u16* wPrjB  = (u16*)(ws + 8650752);     // 1,179,648 B
  float* bufC = (float*)(ws + 9830400);   // 12,582,912 B
  float* bufD = (float*)(ws + 22413312);  // 12,582,912 B
  u16* bufF   = (u16*)(ws + 35782656);    // 6,291,456 B  (total 42,074,112 B)
  u16* xpA    = (u16*)bufC;               // 524,288 B   (alias y1 slot, valid after dwconv7)
  u16* wB     = (u16*)((char*)bufC + 524288);   // 3,145,728 B
  u16* wXdB   = (u16*)((char*)bufC + 3670016);  // 98,304 B
  u16* y2t    = bufF;
  u16* out1T  = lnA;
  u16* y4T    = (u16*)bufD;

  cvt_w<<<dim3(2304, 3), 256, 0, stream>>>(win, wInB, wout, wOutB, wprj, wPrjB);
  ln_k<<<4096, 256, 0, stream>>>(hs, nw, nb, lnA, shortcut);
  gemm_bf16<<<dim3(32, 12), 256, 0, stream>>>(wInB, lnA, bufC, 0);            // in_proj -> y1 [b][o][p]
  dwconv7_k<<<3072, 256, 0, stream>>>(bufC, c7w, c7b, bufD);                  // y2 f32
  transpose_f2b<<<dim3(16, 12, 4), 256, 0, stream>>>(bufD, y2t);              // y2 -> token-major bf16
  wcat_k<<<768, 256, 0, stream>>>(wupw, lupw, uupw, dcow, wB);                // gathered scan weights
  cvt_xd<<<192, 256, 0, stream>>>(xdw, wXdB);                                 // xdown weights, padded
  gemm_bf16<<<dim3(32, 1), 256, 0, stream>>>(wXdB, y2t, (float*)xpA, 2);      // xdown -> xpA (h-major)
  scan_k<<<6144, 256, 0, stream>>>(bufD, xpA, wB, mww, bufF);                 // out1 bf16 [b][c][p]
  transpose_bf16<<<dim3(16, 12, 4), 256, 0, stream>>>(bufF, out1T);           // -> [pg][c]
  gemm_bf16<<<dim3(32, 12), 256, 0, stream>>>(wOutB, out1T, bufC, 0);         // outconv -> y3 [b][o][p]
  dwconv3_k<<<3072, 256, 0, stream>>>(bufC, odw, bufF);                       // dw3 + x*relu(x) -> bf16
  transpose_bf16<<<dim3(16, 12, 4), 256, 0, stream>>>(bufF, y4T);             // -> [pg][c]
  gemm_bf16<<<dim3(32, 12), 256, 0, stream>>>(wPrjB, y4T, out0, 1);           // outproj -> out [b][t][d]
}

// Round 6
// 268.024 us; speedup vs baseline: 1.0510x; 1.0510x over previous
//
#include <hip/hip_runtime.h>

typedef unsigned short u16;
typedef unsigned int u32;
typedef __attribute__((ext_vector_type(8))) short short8v;   // 8 x bf16 (raw bits)
typedef __attribute__((ext_vector_type(4))) float f32x4;

#define DD 768
#define PP 1024
#define NTOK 4096
#define ASN 520   // act row stride (u16), 16B-aligned rows

__device__ __forceinline__ u16 f2bf(float f) {
  u32 u = __builtin_bit_cast(u32, f);
  u += 0x7fffu + ((u >> 16) & 1u);
  return (u16)(u >> 16);
}
__device__ __forceinline__ float b2f(u16 v) {
  return __builtin_bit_cast(float, (u32)v << 16);
}
// extract element j of a bf16x8 register as float (j compile-time after unroll)
__device__ __forceinline__ float ex8(const short8v& v, int j) {
  const u32 dw = ((const u32*)&v)[j >> 1];
  return __builtin_bit_cast(float, (j & 1) ? (dw & 0xffff0000u) : (dw << 16));
}

// ---------------- fused weight prep: cvt 3 big mats + xdown pad + scan-weight gather ----------------
__global__ __launch_bounds__(256) void prep_k(const float* __restrict__ win, u16* __restrict__ wInB,
                                              const float* __restrict__ wout, u16* __restrict__ wOutB,
                                              const float* __restrict__ wprj, u16* __restrict__ wPrjB,
                                              const float* __restrict__ xdw, u16* __restrict__ wXdB,
                                              const float* __restrict__ wup, const float* __restrict__ lup,
                                              const float* __restrict__ uup, const float* __restrict__ dco,
                                              u16* __restrict__ wB) {
  const int id = blockIdx.x;
  const int t = threadIdx.x;
  if (id < 6912) {                       // 3 x 589824 f32 -> bf16
    const int m = id / 2304;
    const int i = (id - m * 2304) * 256 + t;
    const float* s = (m == 0) ? win : (m == 1) ? wout : wprj;
    u16* d = (m == 0) ? wInB : (m == 1) ? wOutB : wPrjB;
    d[i] = f2bf(s[i]);
  } else if (id < 7104) {                // xdown 48x768 -> 64x768 padded bf16
    const int i = (id - 6912) * 256 + t;
    const int r = i / DD;
    wXdB[i] = (r < 48) ? f2bf(xdw[i]) : (u16)0;
  } else {                               // gather scan weights: wB[c][32 rows][64 k]
    const int c = id - 7104;
    u16* dst = wB + (size_t)c * 2048;
    for (int i = t; i < 2048; i += 256) {
      const int row = i >> 6, s = i & 63;
      u16 v = 0;
      if (row < 24 && s < 48) {
        const int k = row & 3, type = row >> 2;
        const int ch = k * DD + c;
        const float* src;
        if (type < 3) src = wup + ((size_t)(type * 3072 + ch)) * 48;
        else if (type == 3) src = lup + (size_t)ch * 48;
        else if (type == 4) src = uup + (size_t)ch * 48;
        else src = dco + (size_t)ch * 48;
        v = f2bf(src[s]);
      }
      dst[i] = v;
    }
  }
}

// ---------------- LayerNorm + shortcut copy ----------------
__global__ __launch_bounds__(256) void ln_k(const float* __restrict__ x,
                                            const float* __restrict__ gw, const float* __restrict__ gb,
                                            u16* __restrict__ lnout, float* __restrict__ shortcut) {
  const int tok = blockIdx.x;
  const int t = threadIdx.x;
  const float* xr = x + (size_t)tok * DD;
  float v0 = xr[t], v1 = xr[t + 256], v2 = xr[t + 512];
  float s = v0 + v1 + v2;
  float q = v0 * v0 + v1 * v1 + v2 * v2;
#pragma unroll
  for (int off = 32; off > 0; off >>= 1) {
    s += __shfl_down(s, off, 64);
    q += __shfl_down(q, off, 64);
  }
  __shared__ float ss[4], qs[4];
  const int wid = t >> 6, lane = t & 63;
  if (lane == 0) { ss[wid] = s; qs[wid] = q; }
  __syncthreads();
  const float st = ss[0] + ss[1] + ss[2] + ss[3];
  const float qt = qs[0] + qs[1] + qs[2] + qs[3];
  const float mu = st * (1.f / 768.f);
  const float var = qt * (1.f / 768.f) - mu * mu;
  const float rstd = rsqrtf(var + 1e-5f);
  float* sc = shortcut + (size_t)tok * DD;
  u16* lo = lnout + (size_t)tok * DD;
  sc[t] = v0; sc[t + 256] = v1; sc[t + 512] = v2;
  lo[t]       = f2bf((v0 - mu) * rstd * gw[t] + gb[t]);
  lo[t + 256] = f2bf((v1 - mu) * rstd * gw[t + 256] + gb[t + 256]);
  lo[t + 512] = f2bf((v2 - mu) * rstd * gw[t + 512] + gb[t + 512]);
}

// ---------------- bf16 MFMA GEMM: out[o,pg] = sum_c A[o,c]*Bt[pg,c] ----------------
// mode 1: store f32 token-major   out[pg*768 + o]
// mode 2: store bf16 to xpA[(b*1024 + i)*64 + o], i = (w>>4)*512 + h*16 + (w&15)
// mode 3: store bf16 channel-major out[(b*768+o)*1024 + p]
__global__ __launch_bounds__(256) void gemm_bf16(const u16* __restrict__ A,
                                                 const u16* __restrict__ Bt,
                                                 void* __restrict__ outv, const int mode) {
  __shared__ u16 Al[64][40];
  __shared__ u16 Bl[128][40];
  const int t = threadIdx.x;
  const int ntile = blockIdx.x * 128;
  const int mtile = blockIdx.y * 64;
  const int wid = t >> 6, lane = t & 63;
  const int m0 = (wid & 1) * 32, n0 = (wid >> 1) * 64;
  const int l15 = lane & 15, quad = lane >> 4;
  f32x4 acc[2][4];
#pragma unroll
  for (int mi = 0; mi < 2; ++mi)
#pragma unroll
    for (int ni = 0; ni < 4; ++ni) acc[mi][ni] = (f32x4){0.f, 0.f, 0.f, 0.f};
  const int ra = t >> 2, sa = t & 3;
  const int rb = t >> 1, hb = t & 1;
  const u16* ag = A + (size_t)(mtile + ra) * DD + sa * 8;
  const u16* bg = Bt + (size_t)(ntile + rb) * DD + hb * 16;
  for (int k0 = 0; k0 < DD; k0 += 32) {
    const uint4 av = *reinterpret_cast<const uint4*>(ag + k0);
    const uint4 bv0 = *reinterpret_cast<const uint4*>(bg + k0);
    const uint4 bv1 = *reinterpret_cast<const uint4*>(bg + k0 + 8);
    __syncthreads();
    *reinterpret_cast<uint4*>(&Al[ra][sa * 8]) = av;
    *reinterpret_cast<uint4*>(&Bl[rb][hb * 16]) = bv0;
    *reinterpret_cast<uint4*>(&Bl[rb][hb * 16 + 8]) = bv1;
    __syncthreads();
    short8v af[2];
#pragma unroll
    for (int mi = 0; mi < 2; ++mi)
      af[mi] = *reinterpret_cast<const short8v*>(&Al[m0 + mi * 16 + l15][quad * 8]);
    short8v bfr[4];
#pragma unroll
    for (int ni = 0; ni < 4; ++ni)
      bfr[ni] = *reinterpret_cast<const short8v*>(&Bl[n0 + ni * 16 + l15][quad * 8]);
#pragma unroll
    for (int mi = 0; mi < 2; ++mi)
#pragma unroll
      for (int ni = 0; ni < 4; ++ni)
        acc[mi][ni] = __builtin_amdgcn_mfma_f32_16x16x32_bf16(af[mi], bfr[ni], acc[mi][ni], 0, 0, 0);
  }
#pragma unroll
  for (int mi = 0; mi < 2; ++mi) {
#pragma unroll
    for (int ni = 0; ni < 4; ++ni) {
      const int ob = mtile + m0 + mi * 16 + quad * 4;
      const int pg = ntile + n0 + ni * 16 + l15;
      if (mode == 1) {
        *reinterpret_cast<f32x4*>((float*)outv + (size_t)pg * DD + ob) = acc[mi][ni];
      } else if (mode == 2) {
        const int bb = pg >> 10, pq = pg & 1023;
        const int q = ((pq & 31) >> 4) * 512 + (pq >> 5) * 16 + (pq & 15);
        u16* dst = (u16*)outv + ((size_t)(bb * 1024 + q)) * 64 + ob;
        const u32 lo = (u32)f2bf(acc[mi][ni][0]) | ((u32)f2bf(acc[mi][ni][1]) << 16);
        const u32 hi = (u32)f2bf(acc[mi][ni][2]) | ((u32)f2bf(acc[mi][ni][3]) << 16);
        *reinterpret_cast<uint2*>(dst) = make_uint2(lo, hi);
      } else {
        const int bb = pg >> 10, pq = pg & 1023;
        u16* dstb = (u16*)outv;
#pragma unroll
        for (int r = 0; r < 4; ++r)
          dstb[((size_t)(bb * DD + ob + r)) * PP + pq] = f2bf(acc[mi][ni][r]);
      }
    }
  }
}

// ---------------- depthwise 7x7 + bias, bf16 -> bf16 ----------------
__global__ __launch_bounds__(256) void dwconv7_k(const u16* __restrict__ x,
                                                 const float* __restrict__ wgt,
                                                 const float* __restrict__ bias,
                                                 u16* __restrict__ y) {
  const int bc = blockIdx.x;
  const int c = bc % DD;
  __shared__ float tile[38 * 38];
  __shared__ float wl[49];
  __shared__ float bsh[1];
  const int t = threadIdx.x;
  for (int i = t; i < 38 * 38; i += 256) tile[i] = 0.f;
  __syncthreads();
  const u16* xr = x + (size_t)bc * PP;
  for (int i = t; i < 512; i += 256) {
    const u32 v = reinterpret_cast<const u32*>(xr)[i];
    const int p0 = i * 2;
    const int h = p0 >> 5, w = p0 & 31;
    tile[(h + 3) * 38 + w + 3] = b2f((u16)v);
    tile[(h + 3) * 38 + w + 4] = b2f((u16)(v >> 16));
  }
  if (t < 49) wl[t] = wgt[c * 49 + t];
  if (t == 0) bsh[0] = bias[c];
  __syncthreads();
  u16* yo = y + (size_t)bc * PP;
  for (int i = t; i < 1024; i += 256) {
    const int h = i >> 5, w = i & 31;
    float acc = bsh[0];
#pragma unroll
    for (int kh = 0; kh < 7; ++kh)
#pragma unroll
      for (int kw = 0; kw < 7; ++kw)
        acc = fmaf(wl[kh * 7 + kw], tile[(h + kh) * 38 + (w + kw)], acc);
    yo[i] = f2bf(acc);
  }
}

// ---------------- depthwise 3x3 (no bias) + x*relu(x), bf16 -> bf16 ----------------
__global__ __launch_bounds__(256) void dwconv3_k(const u16* __restrict__ x,
                                                 const float* __restrict__ wgt,
                                                 u16* __restrict__ y) {
  const int bc = blockIdx.x;
  const int c = bc % DD;
  __shared__ float tile[34 * 34];
  __shared__ float wl[9];
  const int t = threadIdx.x;
  for (int i = t; i < 34 * 34; i += 256) tile[i] = 0.f;
  __syncthreads();
  const u16* xr = x + (size_t)bc * PP;
  for (int i = t; i < 512; i += 256) {
    const u32 v = reinterpret_cast<const u32*>(xr)[i];
    const int p0 = i * 2;
    const int h = p0 >> 5, w = p0 & 31;
    tile[(h + 1) * 34 + w + 1] = b2f((u16)v);
    tile[(h + 1) * 34 + w + 2] = b2f((u16)(v >> 16));
  }
  if (t < 9) wl[t] = wgt[c * 9 + t];
  __syncthreads();
  u16* yo = y + (size_t)bc * PP;
  for (int i = t; i < 1024; i += 256) {
    const int h = i >> 5, w = i & 31;
    float acc = 0.f;
#pragma unroll
    for (int kh = 0; kh < 3; ++kh)
#pragma unroll
      for (int kw = 0; kw < 3; ++kw)
        acc = fmaf(wl[kh * 3 + kw], tile[(h + kh) * 34 + (w + kw)], acc);
    const float r = acc > 0.f ? acc * acc : 0.f;
    yo[i] = f2bf(r);
  }
}

// ---------------- fused MFMA projections + 4-direction chunked scan + recombine ----------------
// grid = 6144: blockIdx.x = bc*2 + half; half selects w in [half*16, half*16+16).
// Phase B: wave wid = (ncl<<1)|dpair; lane = d*32 + h; lane owns direction k = dpair*2+d.
// Gate normalization via p = 1+e^{-a}: gl = pm*pr/S etc, ONE fast rcp, 3 exp. Boundary rows
// handled by clamping e -> 1e30 (gate -> ~1e-30, times the pad value == the reference's 0).
__global__ __launch_bounds__(256, 4) void scan_k(const u16* __restrict__ y2b,
                                                 const u16* __restrict__ xpA,
                                                 const u16* __restrict__ wB,
                                                 const float* __restrict__ mwp,
                                                 u16* __restrict__ out1) {
  const int bid = blockIdx.x;
  const int bc = bid >> 1;
  const int half = bid & 1;
  const int b = bc / DD;
  const int c = bc - b * DD;
  __shared__ u16 act[24 * ASN];       // 24,960 B
  __shared__ float plane[32][33];     //  4,224 B  plane[h][w] = x(h,w)
  __shared__ float planeT[32][33];    //  4,224 B  planeT[h][w] = x(w,h)
  __shared__ float outp[2][16][33];   //  4,224 B
  const int t = threadIdx.x;
  const int wid = t >> 6, lane = t & 63, l15 = lane & 15, quad = lane >> 4;
  {
    const u16* yp = y2b + (size_t)bc * PP;
    for (int i = t; i < 512; i += 256) {
      const u32 v = reinterpret_cast<const u32*>(yp)[i];
      const int p0 = i * 2;
      const int hh = p0 >> 5, ww = p0 & 31;
      const float f0 = b2f((u16)v), f1 = b2f((u16)(v >> 16));
      plane[hh][ww] = f0; plane[hh][ww + 1] = f1;
      planeT[ww][hh] = f0; planeT[ww + 1][hh] = f1;
    }
  }
  // ---- phase A: projections via MFMA (512 i-rows, 128 per wave) ----
  {
    const u16* wc = wB + (size_t)c * 2048;
    short8v bw[2][2];
#pragma unroll
    for (int nt = 0; nt < 2; ++nt)
#pragma unroll
      for (int ks = 0; ks < 2; ++ks)
        bw[nt][ks] = *reinterpret_cast<const short8v*>(wc + (nt * 16 + l15) * 64 + ks * 32 + quad * 8);
    const u16* ab = xpA + ((size_t)(b * 1024 + half * 512 + wid * 128)) * 64;
#pragma unroll 4
    for (int mt = 0; mt < 8; ++mt) {
      const u16* ar = ab + (mt * 16 + l15) * 64 + quad * 8;
      const short8v a0 = *reinterpret_cast<const short8v*>(ar);
      const short8v a1 = *reinterpret_cast<const short8v*>(ar + 32);
      f32x4 acc0 = {0.f, 0.f, 0.f, 0.f}, acc1 = {0.f, 0.f, 0.f, 0.f};
      acc0 = __builtin_amdgcn_mfma_f32_16x16x32_bf16(a0, bw[0][0], acc0, 0, 0, 0);
      acc0 = __builtin_amdgcn_mfma_f32_16x16x32_bf16(a1, bw[0][1], acc0, 0, 0, 0);
      acc1 = __builtin_amdgcn_mfma_f32_16x16x32_bf16(a0, bw[1][0], acc1, 0, 0, 0);
      acc1 = __builtin_amdgcn_mfma_f32_16x16x32_bf16(a1, bw[1][1], acc1, 0, 0, 0);
      const int qb = wid * 128 + mt * 16 + quad * 4;
      const u32 lo0 = (u32)f2bf(acc0[0]) | ((u32)f2bf(acc0[1]) << 16);
      const u32 hi0 = (u32)f2bf(acc0[2]) | ((u32)f2bf(acc0[3]) << 16);
      *reinterpret_cast<uint2*>(&act[l15 * ASN + qb]) = make_uint2(lo0, hi0);
      if (l15 < 8) {
        const u32 lo1 = (u32)f2bf(acc1[0]) | ((u32)f2bf(acc1[1]) << 16);
        const u32 hi1 = (u32)f2bf(acc1[2]) | ((u32)f2bf(acc1[3]) << 16);
        *reinterpret_cast<uint2*>(&act[(16 + l15) * ASN + qb]) = make_uint2(lo1, hi1);
      }
    }
  }
  __syncthreads();
  // ---- phase B: chunked scan, one direction per lane ----
  const int dpair = wid & 1;
  const int ncl = wid >> 1;
  const int d = lane >> 5;
  const int h = lane & 31;
  const int k = dpair * 2 + d;
  const float mw = mwp[k];
  const int base16 = h * 16 + ncl * 8;
  const short8v vGl = *reinterpret_cast<const short8v*>(&act[(0  + k) * ASN + base16]);
  const short8v vGm = *reinterpret_cast<const short8v*>(&act[(4  + k) * ASN + base16]);
  const short8v vGr = *reinterpret_cast<const short8v*>(&act[(8  + k) * ASN + base16]);
  const short8v vL  = *reinterpret_cast<const short8v*>(&act[(12 + k) * ASN + base16]);
  const short8v vU  = *reinterpret_cast<const short8v*>(&act[(16 + k) * ASN + base16]);
  const short8v vD  = *reinterpret_cast<const short8v*>(&act[(20 + k) * ASN + base16]);
  const float* prow = (d == 0) ? &plane[h][0] : &planeT[h][0];
  const bool top = (h == 0), bot = (h == 31);
  float H = 0.f;
#pragma unroll
  for (int j = 0; j < 8; ++j) {
    const int w = half * 16 + ncl * 8 + j;
    const int wc_ = dpair ? (31 - w) : w;
    const float xv = prow[wc_];
    float el = __expf(-ex8(vGl, j));
    const float em = __expf(-ex8(vGm, j));
    float er = __expf(-ex8(vGr, j));
    if (top) el = 1e30f;
    if (bot) er = 1e30f;
    const float pl = 1.f + el, pm = 1.f + em, pr = 1.f + er;
    const float ul = pm * pr, um = pl * pr, ur = pl * pm;
    const float rcpS = __builtin_amdgcn_rcpf(ul + um + ur);
    const float up = __shfl(H, lane - 1, 64);
    const float dn = __shfl(H, lane + 1, 64);
    H = fmaf(ex8(vL, j), xv, (fmaf(ul, up, fmaf(um, H, ur * dn))) * rcpS);
    float part = mw * fmaf(H, ex8(vU, j), xv * ex8(vD, j));
    part += __shfl_xor(part, 32, 64);
    if (d == 0) outp[dpair][ncl * 8 + j][h] = part;
  }
  __syncthreads();
  const int hh = t >> 3, wp = t & 7;
  const float v0 = outp[0][wp * 2][hh] + outp[1][wp * 2][hh];
  const float v1 = outp[0][wp * 2 + 1][hh] + outp[1][wp * 2 + 1][hh];
  const u32 pk = (u32)f2bf(v0) | ((u32)f2bf(v1) << 16);
  *reinterpret_cast<u32*>(out1 + (size_t)bc * PP + hh * 32 + half * 16 + wp * 2) = pk;
}

// ---------------- bf16 transpose: [b][c][p] -> [(b*1024+p)][c] ----------------
__global__ __launch_bounds__(256) void transpose_bf16(const u16* __restrict__ in,
                                                      u16* __restrict__ out) {
  __shared__ u16 tile[64][72];
  const int b = blockIdx.z;
  const int c0 = blockIdx.y * 64;
  const int p0 = blockIdx.x * 64;
  const int t = threadIdx.x;
  const int r = t >> 2, s2 = t & 3;
  const u16* src = in + ((size_t)(b * DD + c0 + r)) * PP + p0 + s2 * 16;
  *reinterpret_cast<uint4*>(&tile[r][s2 * 16]) = *reinterpret_cast<const uint4*>(src);
  *reinterpret_cast<uint4*>(&tile[r][s2 * 16 + 8]) = *reinterpret_cast<const uint4*>(src + 8);
  __syncthreads();
  const int pr = t >> 2, cs = t & 3;
  union { u16 u[16]; uint4 v[2]; } vals;
#pragma unroll
  for (int i = 0; i < 16; ++i) vals.u[i] = tile[cs * 16 + i][pr];
  u16* dst = out + ((size_t)(b * 1024 + p0 + pr)) * DD + c0 + cs * 16;
  reinterpret_cast<uint4*>(dst)[0] = vals.v[0];
  reinterpret_cast<uint4*>(dst)[1] = vals.v[1];
}

extern "C" void kernel_launch(void* const* d_in, const int* in_sizes, int n_in,
                              void* d_out, int out_size, void* d_ws, size_t ws_size,
                              hipStream_t stream) {
  const float* hs   = (const float*)d_in[0];
  const float* nw   = (const float*)d_in[1];
  const float* nb   = (const float*)d_in[2];
  const float* win  = (const float*)d_in[3];
  const float* c7w  = (const float*)d_in[4];
  const float* c7b  = (const float*)d_in[5];
  const float* xdw  = (const float*)d_in[6];
  const float* wupw = (const float*)d_in[7];
  const float* lupw = (const float*)d_in[8];
  const float* uupw = (const float*)d_in[9];
  const float* dcow = (const float*)d_in[10];
  const float* mww  = (const float*)d_in[11];
  const float* wout = (const float*)d_in[12];
  const float* odw  = (const float*)d_in[13];
  const float* wprj = (const float*)d_in[14];
  float* out0 = (float*)d_out;
  float* shortcut = out0 + (size_t)NTOK * DD;

  char* ws = (char*)d_ws;
  u16* lnA    = (u16*)(ws + 0);            // 6,291,456  ln->gemm1; later out1T
  u16* wInB   = (u16*)(ws + 6291456);      // 1,179,648
  u16* wOutB  = (u16*)(ws + 7471104);      // 1,179,648
  u16* wPrjB  = (u16*)(ws + 8650752);      // 1,179,648
  u16* wB     = (u16*)(ws + 9830400);      // 3,145,728
  u16* wXdB   = (u16*)(ws + 12976128);     //    98,304
  u16* xpA    = (u16*)(ws + 13074432);     //   524,288
  u16* y1b    = (u16*)(ws + 13598720);     // 6,291,456  gemm1->dw7; later y3b (gemm3->dw3)
  u16* y2b    = (u16*)(ws + 19890176);     // 6,291,456  dw7->{transpose,scan}; later y4b
  u16* y2t    = (u16*)(ws + 26181632);     // 6,291,456  transpose->xdgemm; later y4T
  u16* out1   = (u16*)(ws + 32473088);     // 6,291,456  scan->transpose   (total 38,764,544)
  u16* out1T  = lnA;
  u16* y3b    = y1b;
  u16* y4b    = y2b;
  u16* y4T    = y2t;

  prep_k<<<7872, 256, 0, stream>>>(win, wInB, wout, wOutB, wprj, wPrjB,
                                   xdw, wXdB, wupw, lupw, uupw, dcow, wB);
  ln_k<<<4096, 256, 0, stream>>>(hs, nw, nb, lnA, shortcut);
  gemm_bf16<<<dim3(32, 12), 256, 0, stream>>>(wInB, lnA, y1b, 3);             // in_proj -> y1 bf16 [b][o][p]
  dwconv7_k<<<3072, 256, 0, stream>>>(y1b, c7w, c7b, y2b);                    // y2 bf16
  transpose_bf16<<<dim3(16, 12, 4), 256, 0, stream>>>(y2b, y2t);              // y2 -> token-major
  gemm_bf16<<<dim3(32, 1), 256, 0, stream>>>(wXdB, y2t, xpA, 2);              // xdown -> xpA (h-major)
  scan_k<<<6144, 256, 0, stream>>>(y2b, xpA, wB, mww, out1);                  // out1 bf16 [b][c][p]
  transpose_bf16<<<dim3(16, 12, 4), 256, 0, stream>>>(out1, out1T);           // -> [pg][c]
  gemm_bf16<<<dim3(32, 12), 256, 0, stream>>>(wOutB, out1T, y3b, 3);          // outconv -> y3 bf16 [b][o][p]
  dwconv3_k<<<3072, 256, 0, stream>>>(y3b, odw, y4b);                         // dw3 + x*relu(x) -> bf16
  transpose_bf16<<<dim3(16, 12, 4), 256, 0, stream>>>(y4b, y4T);              // -> [pg][c]
  gemm_bf16<<<dim3(32, 12), 256, 0, stream>>>(wPrjB, y4T, out0, 1);           // outproj -> out [b][t][d]
}

// Round 7
// 262.957 us; speedup vs baseline: 1.0712x; 1.0193x over previous
//
#include <hip/hip_runtime.h>

typedef unsigned short u16;
typedef unsigned int u32;
typedef __attribute__((ext_vector_type(8))) short short8v;   // 8 x bf16 (raw bits)
typedef __attribute__((ext_vector_type(4))) float f32x4;

#define DD 768
#define PP 1024
#define NTOK 4096
#define ASN 520   // act row stride (u16), 16B-aligned rows

__device__ __forceinline__ u16 f2bf(float f) {
  u32 u = __builtin_bit_cast(u32, f);
  u += 0x7fffu + ((u >> 16) & 1u);
  return (u16)(u >> 16);
}
__device__ __forceinline__ float b2f(u16 v) {
  return __builtin_bit_cast(float, (u32)v << 16);
}
// pack hi16(fa)<<16 | hi16(fb) in ONE v_perm_b32 (truncating bf16 pack)
__device__ __forceinline__ u32 pk_trunc(float fa, float fb) {
  return __builtin_amdgcn_perm(__builtin_bit_cast(u32, fa), __builtin_bit_cast(u32, fb), 0x07060302u);
}
// extract element j of a bf16x8 register as float (j compile-time after unroll)
__device__ __forceinline__ float ex8(const short8v& v, int j) {
  const u32 dw = ((const u32*)&v)[j >> 1];
  return __builtin_bit_cast(float, (j & 1) ? (dw & 0xffff0000u) : (dw << 16));
}

// ---------------- fused: LayerNorm+shortcut  AND  all weight prep ----------------
__global__ __launch_bounds__(256) void prep_ln_k(const float* __restrict__ hs,
                                                 const float* __restrict__ gw, const float* __restrict__ gb,
                                                 u16* __restrict__ lnout, float* __restrict__ shortcut,
                                                 const float* __restrict__ win, u16* __restrict__ wInB,
                                                 const float* __restrict__ wout, u16* __restrict__ wOutB,
                                                 const float* __restrict__ wprj, u16* __restrict__ wPrjB,
                                                 const float* __restrict__ xdw, u16* __restrict__ wXdB,
                                                 const float* __restrict__ wup, const float* __restrict__ lup,
                                                 const float* __restrict__ uup, const float* __restrict__ dco,
                                                 u16* __restrict__ wB) {
  const int id = blockIdx.x;
  const int t = threadIdx.x;
  if (id < 4096) {                       // -------- LayerNorm on token id --------
    const int tok = id;
    const float* xr = hs + (size_t)tok * DD;
    float v0 = xr[t], v1 = xr[t + 256], v2 = xr[t + 512];
    float s = v0 + v1 + v2;
    float q = v0 * v0 + v1 * v1 + v2 * v2;
#pragma unroll
    for (int off = 32; off > 0; off >>= 1) {
      s += __shfl_down(s, off, 64);
      q += __shfl_down(q, off, 64);
    }
    __shared__ float ss[4], qs[4];
    const int wid = t >> 6, lane = t & 63;
    if (lane == 0) { ss[wid] = s; qs[wid] = q; }
    __syncthreads();
    const float st = ss[0] + ss[1] + ss[2] + ss[3];
    const float qt = qs[0] + qs[1] + qs[2] + qs[3];
    const float mu = st * (1.f / 768.f);
    const float var = qt * (1.f / 768.f) - mu * mu;
    const float rstd = rsqrtf(var + 1e-5f);
    float* sc = shortcut + (size_t)tok * DD;
    u16* lo = lnout + (size_t)tok * DD;
    sc[t] = v0; sc[t + 256] = v1; sc[t + 512] = v2;
    lo[t]       = f2bf((v0 - mu) * rstd * gw[t] + gb[t]);
    lo[t + 256] = f2bf((v1 - mu) * rstd * gw[t + 256] + gb[t + 256]);
    lo[t + 512] = f2bf((v2 - mu) * rstd * gw[t + 512] + gb[t + 512]);
    return;
  }
  const int id2 = id - 4096;
  if (id2 < 6912) {                      // -------- 3 x 589824 f32 -> bf16 --------
    const int m = id2 / 2304;
    const int i = (id2 - m * 2304) * 256 + t;
    const float* s = (m == 0) ? win : (m == 1) ? wout : wprj;
    u16* d = (m == 0) ? wInB : (m == 1) ? wOutB : wPrjB;
    d[i] = f2bf(s[i]);
  } else if (id2 < 7104) {               // -------- xdown 48x768 -> 64x768 padded --------
    const int i = (id2 - 6912) * 256 + t;
    const int r = i / DD;
    wXdB[i] = (r < 48) ? f2bf(xdw[i]) : (u16)0;
  } else {                               // -------- gather scan weights --------
    const int c = id2 - 7104;
    u16* dst = wB + (size_t)c * 2048;
    for (int i = t; i < 2048; i += 256) {
      const int row = i >> 6, s = i & 63;
      u16 v = 0;
      if (row < 24 && s < 48) {
        const int k = row & 3, type = row >> 2;
        const int ch = k * DD + c;
        const float* src;
        if (type < 3) src = wup + ((size_t)(type * 3072 + ch)) * 48;
        else if (type == 3) src = lup + (size_t)ch * 48;
        else if (type == 4) src = uup + (size_t)ch * 48;
        else src = dco + (size_t)ch * 48;
        v = f2bf(src[s]);
      }
      dst[i] = v;
    }
  }
}

// ---------------- bf16 MFMA GEMM: out[o,pg] = sum_c A[o,c]*Bt[pg,c] ----------------
// mode 1: store f32 token-major   out[pg*768 + o]
// mode 2: store bf16 to xpA[(b*1024 + i)*64 + o], i = (w>>4)*512 + h*16 + (w&15)
// mode 3: store bf16 channel-major out[(b*768+o)*1024 + p]
__global__ __launch_bounds__(256) void gemm_bf16(const u16* __restrict__ A,
                                                 const u16* __restrict__ Bt,
                                                 void* __restrict__ outv, const int mode) {
  __shared__ u16 Al[64][40];
  __shared__ u16 Bl[128][40];
  const int t = threadIdx.x;
  const int ntile = blockIdx.x * 128;
  const int mtile = blockIdx.y * 64;
  const int wid = t >> 6, lane = t & 63;
  const int m0 = (wid & 1) * 32, n0 = (wid >> 1) * 64;
  const int l15 = lane & 15, quad = lane >> 4;
  f32x4 acc[2][4];
#pragma unroll
  for (int mi = 0; mi < 2; ++mi)
#pragma unroll
    for (int ni = 0; ni < 4; ++ni) acc[mi][ni] = (f32x4){0.f, 0.f, 0.f, 0.f};
  const int ra = t >> 2, sa = t & 3;
  const int rb = t >> 1, hb = t & 1;
  const u16* ag = A + (size_t)(mtile + ra) * DD + sa * 8;
  const u16* bg = Bt + (size_t)(ntile + rb) * DD + hb * 16;
  for (int k0 = 0; k0 < DD; k0 += 32) {
    const uint4 av = *reinterpret_cast<const uint4*>(ag + k0);
    const uint4 bv0 = *reinterpret_cast<const uint4*>(bg + k0);
    const uint4 bv1 = *reinterpret_cast<const uint4*>(bg + k0 + 8);
    __syncthreads();
    *reinterpret_cast<uint4*>(&Al[ra][sa * 8]) = av;
    *reinterpret_cast<uint4*>(&Bl[rb][hb * 16]) = bv0;
    *reinterpret_cast<uint4*>(&Bl[rb][hb * 16 + 8]) = bv1;
    __syncthreads();
    short8v af[2];
#pragma unroll
    for (int mi = 0; mi < 2; ++mi)
      af[mi] = *reinterpret_cast<const short8v*>(&Al[m0 + mi * 16 + l15][quad * 8]);
    short8v bfr[4];
#pragma unroll
    for (int ni = 0; ni < 4; ++ni)
      bfr[ni] = *reinterpret_cast<const short8v*>(&Bl[n0 + ni * 16 + l15][quad * 8]);
#pragma unroll
    for (int mi = 0; mi < 2; ++mi)
#pragma unroll
      for (int ni = 0; ni < 4; ++ni)
        acc[mi][ni] = __builtin_amdgcn_mfma_f32_16x16x32_bf16(af[mi], bfr[ni], acc[mi][ni], 0, 0, 0);
  }
#pragma unroll
  for (int mi = 0; mi < 2; ++mi) {
#pragma unroll
    for (int ni = 0; ni < 4; ++ni) {
      const int ob = mtile + m0 + mi * 16 + quad * 4;
      const int pg = ntile + n0 + ni * 16 + l15;
      if (mode == 1) {
        *reinterpret_cast<f32x4*>((float*)outv + (size_t)pg * DD + ob) = acc[mi][ni];
      } else if (mode == 2) {
        const int bb = pg >> 10, pq = pg & 1023;
        const int q = ((pq & 31) >> 4) * 512 + (pq >> 5) * 16 + (pq & 15);
        u16* dst = (u16*)outv + ((size_t)(bb * 1024 + q)) * 64 + ob;
        const u32 lo = (u32)f2bf(acc[mi][ni][0]) | ((u32)f2bf(acc[mi][ni][1]) << 16);
        const u32 hi = (u32)f2bf(acc[mi][ni][2]) | ((u32)f2bf(acc[mi][ni][3]) << 16);
        *reinterpret_cast<uint2*>(dst) = make_uint2(lo, hi);
      } else {
        const int bb = pg >> 10, pq = pg & 1023;
        u16* dstb = (u16*)outv;
#pragma unroll
        for (int r = 0; r < 4; ++r)
          dstb[((size_t)(bb * DD + ob + r)) * PP + pq] = f2bf(acc[mi][ni][r]);
      }
    }
  }
}

// ---------------- depthwise 7x7 + bias, bf16 -> bf16 ----------------
__global__ __launch_bounds__(256) void dwconv7_k(const u16* __restrict__ x,
                                                 const float* __restrict__ wgt,
                                                 const float* __restrict__ bias,
                                                 u16* __restrict__ y) {
  const int bc = blockIdx.x;
  const int c = bc % DD;
  __shared__ float tile[38 * 38];
  __shared__ float wl[49];
  __shared__ float bsh[1];
  const int t = threadIdx.x;
  for (int i = t; i < 38 * 38; i += 256) tile[i] = 0.f;
  __syncthreads();
  const u16* xr = x + (size_t)bc * PP;
  for (int i = t; i < 512; i += 256) {
    const u32 v = reinterpret_cast<const u32*>(xr)[i];
    const int p0 = i * 2;
    const int h = p0 >> 5, w = p0 & 31;
    tile[(h + 3) * 38 + w + 3] = b2f((u16)v);
    tile[(h + 3) * 38 + w + 4] = b2f((u16)(v >> 16));
  }
  if (t < 49) wl[t] = wgt[c * 49 + t];
  if (t == 0) bsh[0] = bias[c];
  __syncthreads();
  u16* yo = y + (size_t)bc * PP;
  for (int i = t; i < 1024; i += 256) {
    const int h = i >> 5, w = i & 31;
    float acc = bsh[0];
#pragma unroll
    for (int kh = 0; kh < 7; ++kh)
#pragma unroll
      for (int kw = 0; kw < 7; ++kw)
        acc = fmaf(wl[kh * 7 + kw], tile[(h + kh) * 38 + (w + kw)], acc);
    yo[i] = f2bf(acc);
  }
}

// ---------------- depthwise 3x3 (no bias) + x*relu(x), bf16 -> bf16 ----------------
__global__ __launch_bounds__(256) void dwconv3_k(const u16* __restrict__ x,
                                                 const float* __restrict__ wgt,
                                                 u16* __restrict__ y) {
  const int bc = blockIdx.x;
  const int c = bc % DD;
  __shared__ float tile[34 * 34];
  __shared__ float wl[9];
  const int t = threadIdx.x;
  for (int i = t; i < 34 * 34; i += 256) tile[i] = 0.f;
  __syncthreads();
  const u16* xr = x + (size_t)bc * PP;
  for (int i = t; i < 512; i += 256) {
    const u32 v = reinterpret_cast<const u32*>(xr)[i];
    const int p0 = i * 2;
    const int h = p0 >> 5, w = p0 & 31;
    tile[(h + 1) * 34 + w + 1] = b2f((u16)v);
    tile[(h + 1) * 34 + w + 2] = b2f((u16)(v >> 16));
  }
  if (t < 9) wl[t] = wgt[c * 9 + t];
  __syncthreads();
  u16* yo = y + (size_t)bc * PP;
  for (int i = t; i < 1024; i += 256) {
    const int h = i >> 5, w = i & 31;
    float acc = 0.f;
#pragma unroll
    for (int kh = 0; kh < 3; ++kh)
#pragma unroll
      for (int kw = 0; kw < 3; ++kw)
        acc = fmaf(wl[kh * 3 + kw], tile[(h + kh) * 34 + (w + kw)], acc);
    const float r = acc > 0.f ? acc * acc : 0.f;
    yo[i] = f2bf(r);
  }
}

// ---------------- fused MFMA projections + 4-direction chunked scan + recombine ----------------
// grid = 6144: blockIdx.x = bc*2 + half; half selects w in [half*16, half*16+16).
// LDS 31,488 B -> 5 blocks/CU. Phase B: gate-precompute pass (no H dep) + tight serial pass.
__global__ __launch_bounds__(256, 5) void scan_k(const u16* __restrict__ y2b,
                                                 const u16* __restrict__ xpA,
                                                 const u16* __restrict__ wB,
                                                 const float* __restrict__ mwp,
                                                 u16* __restrict__ out1) {
  const int bid = blockIdx.x;
  const int bc = bid >> 1;
  const int half = bid & 1;
  const int b = bc / DD;
  const int c = bc - b * DD;
  __shared__ u16 act[24 * ASN];       // 24,960 B
  __shared__ u16 planeb[32][34];      //  2,176 B  planeb[h][w] = x(h,w)
  __shared__ u16 planeTb[32][34];     //  2,176 B  planeTb[h][w] = x(w,h)
  __shared__ u16 outpb[2][16][34];    //  2,176 B   (total 31,488)
  const int t = threadIdx.x;
  const int wid = t >> 6, lane = t & 63, l15 = lane & 15, quad = lane >> 4;
  {
    const u16* yp = y2b + (size_t)bc * PP;
    for (int i = t; i < 512; i += 256) {
      const u32 v = reinterpret_cast<const u32*>(yp)[i];
      const int p0 = i * 2;
      const int hh = p0 >> 5, ww = p0 & 31;
      *reinterpret_cast<u32*>(&planeb[hh][ww]) = v;
      planeTb[ww][hh] = (u16)v;
      planeTb[ww + 1][hh] = (u16)(v >> 16);
    }
  }
  // ---- phase A: projections via MFMA (512 i-rows, 128 per wave) ----
  {
    const u16* wc = wB + (size_t)c * 2048;
    short8v bw[2][2];
#pragma unroll
    for (int nt = 0; nt < 2; ++nt)
#pragma unroll
      for (int ks = 0; ks < 2; ++ks)
        bw[nt][ks] = *reinterpret_cast<const short8v*>(wc + (nt * 16 + l15) * 64 + ks * 32 + quad * 8);
    const u16* ab = xpA + ((size_t)(b * 1024 + half * 512 + wid * 128)) * 64;
#pragma unroll 4
    for (int mt = 0; mt < 8; ++mt) {
      const u16* ar = ab + (mt * 16 + l15) * 64 + quad * 8;
      const short8v a0 = *reinterpret_cast<const short8v*>(ar);
      const short8v a1 = *reinterpret_cast<const short8v*>(ar + 32);
      f32x4 acc0 = {0.f, 0.f, 0.f, 0.f}, acc1 = {0.f, 0.f, 0.f, 0.f};
      acc0 = __builtin_amdgcn_mfma_f32_16x16x32_bf16(a0, bw[0][0], acc0, 0, 0, 0);
      acc0 = __builtin_amdgcn_mfma_f32_16x16x32_bf16(a1, bw[0][1], acc0, 0, 0, 0);
      acc1 = __builtin_amdgcn_mfma_f32_16x16x32_bf16(a0, bw[1][0], acc1, 0, 0, 0);
      acc1 = __builtin_amdgcn_mfma_f32_16x16x32_bf16(a1, bw[1][1], acc1, 0, 0, 0);
      const int qb = wid * 128 + mt * 16 + quad * 4;
      *reinterpret_cast<uint2*>(&act[l15 * ASN + qb]) =
          make_uint2(pk_trunc(acc0[1], acc0[0]), pk_trunc(acc0[3], acc0[2]));
      if (l15 < 8)
        *reinterpret_cast<uint2*>(&act[(16 + l15) * ASN + qb]) =
            make_uint2(pk_trunc(acc1[1], acc1[0]), pk_trunc(acc1[3], acc1[2]));
    }
  }
  __syncthreads();
  // ---- phase B: chunked scan, one direction per lane ----
  const int dpair = wid & 1;
  const int ncl = wid >> 1;
  const int d = lane >> 5;
  const int h = lane & 31;
  const int k = dpair * 2 + d;
  const float mw = mwp[k];
  const int base16 = h * 16 + ncl * 8;
  const short8v vGl = *reinterpret_cast<const short8v*>(&act[(0  + k) * ASN + base16]);
  const short8v vGm = *reinterpret_cast<const short8v*>(&act[(4  + k) * ASN + base16]);
  const short8v vGr = *reinterpret_cast<const short8v*>(&act[(8  + k) * ASN + base16]);
  const short8v vL  = *reinterpret_cast<const short8v*>(&act[(12 + k) * ASN + base16]);
  const short8v vU  = *reinterpret_cast<const short8v*>(&act[(16 + k) * ASN + base16]);
  const short8v vD  = *reinterpret_cast<const short8v*>(&act[(20 + k) * ASN + base16]);
  const u16* prow = (d == 0) ? &planeb[h][0] : &planeTb[h][0];
  const bool top = (h == 0), bot = (h == 31);
  // gate-precompute pass (no dependence on H)
  float gl[8], gm[8], gr[8], Lx[8], xvv[8];
#pragma unroll
  for (int j = 0; j < 8; ++j) {
    const int w = half * 16 + ncl * 8 + j;
    const int wc_ = dpair ? (31 - w) : w;
    const float xv = b2f(prow[wc_]);
    float el = __expf(-ex8(vGl, j));
    const float em = __expf(-ex8(vGm, j));
    float er = __expf(-ex8(vGr, j));
    if (top) el = 1e30f;
    if (bot) er = 1e30f;
    const float pl = 1.f + el, pm = 1.f + em, pr = 1.f + er;
    const float ul = pm * pr, um = pl * pr, ur = pl * pm;
    const float rcpS = __builtin_amdgcn_rcpf(ul + um + ur);
    gl[j] = ul * rcpS; gm[j] = um * rcpS; gr[j] = ur * rcpS;
    Lx[j] = ex8(vL, j) * xv;
    xvv[j] = xv;
  }
  // tight serial pass: per j = 2 bpermutes + 3 chained FMAs
  float H = 0.f;
#pragma unroll
  for (int j = 0; j < 8; ++j) {
    const float up = __shfl(H, lane - 1, 64);
    const float dn = __shfl(H, lane + 1, 64);
    H = fmaf(gl[j], up, fmaf(gm[j], H, fmaf(gr[j], dn, Lx[j])));
    float part = fmaf(H, ex8(vU, j), xvv[j] * ex8(vD, j)) * mw;
    part += __shfl_xor(part, 32, 64);
    if (d == 0)
      outpb[dpair][ncl * 8 + j][h] = (u16)(__builtin_bit_cast(u32, part) >> 16);
  }
  __syncthreads();
  const int hh = t >> 3, wp = t & 7;
  const float v0 = b2f(outpb[0][wp * 2][hh]) + b2f(outpb[1][wp * 2][hh]);
  const float v1 = b2f(outpb[0][wp * 2 + 1][hh]) + b2f(outpb[1][wp * 2 + 1][hh]);
  const u32 pk = pk_trunc(v1, v0);
  *reinterpret_cast<u32*>(out1 + (size_t)bc * PP + hh * 32 + half * 16 + wp * 2) = pk;
}

// ---------------- bf16 transpose: [b][c][p] -> [(b*1024+p)][c] ----------------
__global__ __launch_bounds__(256) void transpose_bf16(const u16* __restrict__ in,
                                                      u16* __restrict__ out) {
  __shared__ u16 tile[64][72];
  const int b = blockIdx.z;
  const int c0 = blockIdx.y * 64;
  const int p0 = blockIdx.x * 64;
  const int t = threadIdx.x;
  const int r = t >> 2, s2 = t & 3;
  const u16* src = in + ((size_t)(b * DD + c0 + r)) * PP + p0 + s2 * 16;
  *reinterpret_cast<uint4*>(&tile[r][s2 * 16]) = *reinterpret_cast<const uint4*>(src);
  *reinterpret_cast<uint4*>(&tile[r][s2 * 16 + 8]) = *reinterpret_cast<const uint4*>(src + 8);
  __syncthreads();
  const int pr = t >> 2, cs = t & 3;
  union { u16 u[16]; uint4 v[2]; } vals;
#pragma unroll
  for (int i = 0; i < 16; ++i) vals.u[i] = tile[cs * 16 + i][pr];
  u16* dst = out + ((size_t)(b * 1024 + p0 + pr)) * DD + c0 + cs * 16;
  reinterpret_cast<uint4*>(dst)[0] = vals.v[0];
  reinterpret_cast<uint4*>(dst)[1] = vals.v[1];
}

extern "C" void kernel_launch(void* const* d_in, const int* in_sizes, int n_in,
                              void* d_out, int out_size, void* d_ws, size_t ws_size,
                              hipStream_t stream) {
  const float* hs   = (const float*)d_in[0];
  const float* nw   = (const float*)d_in[1];
  const float* nb   = (const float*)d_in[2];
  const float* win  = (const float*)d_in[3];
  const float* c7w  = (const float*)d_in[4];
  const float* c7b  = (const float*)d_in[5];
  const float* xdw  = (const float*)d_in[6];
  const float* wupw = (const float*)d_in[7];
  const float* lupw = (const float*)d_in[8];
  const float* uupw = (const float*)d_in[9];
  const float* dcow = (const float*)d_in[10];
  const float* mww  = (const float*)d_in[11];
  const float* wout = (const float*)d_in[12];
  const float* odw  = (const float*)d_in[13];
  const float* wprj = (const float*)d_in[14];
  float* out0 = (float*)d_out;
  float* shortcut = out0 + (size_t)NTOK * DD;

  char* ws = (char*)d_ws;
  u16* lnA    = (u16*)(ws + 0);            // 6,291,456  ln->gemm1; later out1T
  u16* wInB   = (u16*)(ws + 6291456);      // 1,179,648
  u16* wOutB  = (u16*)(ws + 7471104);      // 1,179,648
  u16* wPrjB  = (u16*)(ws + 8650752);      // 1,179,648
  u16* wB     = (u16*)(ws + 9830400);      // 3,145,728
  u16* wXdB   = (u16*)(ws + 12976128);     //    98,304
  u16* xpA    = (u16*)(ws + 13074432);     //   524,288
  u16* y1b    = (u16*)(ws + 13598720);     // 6,291,456  gemm1->dw7; later y3b
  u16* y2b    = (u16*)(ws + 19890176);     // 6,291,456  dw7->{transpose,scan}; later y4b
  u16* y2t    = (u16*)(ws + 26181632);     // 6,291,456  transpose->xdgemm; later y4T
  u16* out1   = (u16*)(ws + 32473088);     // 6,291,456  scan->transpose
  u16* out1T  = lnA;
  u16* y3b    = y1b;
  u16* y4b    = y2b;
  u16* y4T    = y2t;

  prep_ln_k<<<11968, 256, 0, stream>>>(hs, nw, nb, lnA, shortcut,
                                       win, wInB, wout, wOutB, wprj, wPrjB,
                                       xdw, wXdB, wupw, lupw, uupw, dcow, wB);
  gemm_bf16<<<dim3(32, 12), 256, 0, stream>>>(wInB, lnA, y1b, 3);             // in_proj -> y1 bf16
  dwconv7_k<<<3072, 256, 0, stream>>>(y1b, c7w, c7b, y2b);                    // y2 bf16
  transpose_bf16<<<dim3(16, 12, 4), 256, 0, stream>>>(y2b, y2t);              // y2 -> token-major
  gemm_bf16<<<dim3(32, 1), 256, 0, stream>>>(wXdB, y2t, xpA, 2);              // xdown -> xpA
  scan_k<<<6144, 256, 0, stream>>>(y2b, xpA, wB, mww, out1);                  // out1 bf16
  transpose_bf16<<<dim3(16, 12, 4), 256, 0, stream>>>(out1, out1T);           // -> [pg][c]
  gemm_bf16<<<dim3(32, 12), 256, 0, stream>>>(wOutB, out1T, y3b, 3);          // outconv -> y3 bf16
  dwconv3_k<<<3072, 256, 0, stream>>>(y3b, odw, y4b);                         // dw3 + x*relu(x)
  transpose_bf16<<<dim3(16, 12, 4), 256, 0, stream>>>(y4b, y4T);              // -> [pg][c]
  gemm_bf16<<<dim3(32, 12), 256, 0, stream>>>(wPrjB, y4T, out0, 1);           // outproj -> out
}

// Round 8
// 248.315 us; speedup vs baseline: 1.1344x; 1.0590x over previous
//
#include <hip/hip_runtime.h>

typedef unsigned short u16;
typedef unsigned int u32;
typedef __attribute__((ext_vector_type(8))) short short8v;   // 8 x bf16 (raw bits)
typedef __attribute__((ext_vector_type(4))) float f32x4;

#define DD 768
#define PP 1024
#define NTOK 4096
#define ASN 520   // act row stride (u16), 16B-aligned rows

__device__ __forceinline__ u16 f2bf(float f) {
  u32 u = __builtin_bit_cast(u32, f);
  u += 0x7fffu + ((u >> 16) & 1u);
  return (u16)(u >> 16);
}
__device__ __forceinline__ float b2f(u16 v) {
  return __builtin_bit_cast(float, (u32)v << 16);
}
// pack hi16(fa)<<16 | hi16(fb) in ONE v_perm_b32 (truncating bf16 pack)
__device__ __forceinline__ u32 pk_trunc(float fa, float fb) {
  return __builtin_amdgcn_perm(__builtin_bit_cast(u32, fa), __builtin_bit_cast(u32, fb), 0x07060302u);
}
// extract element j of a bf16x8 register as float (j compile-time after unroll)
__device__ __forceinline__ float ex8(const short8v& v, int j) {
  const u32 dw = ((const u32*)&v)[j >> 1];
  return __builtin_bit_cast(float, (j & 1) ? (dw & 0xffff0000u) : (dw << 16));
}

// ---------------- fused: LayerNorm+shortcut  AND  all weight prep ----------------
__global__ __launch_bounds__(256) void prep_ln_k(const float* __restrict__ hs,
                                                 const float* __restrict__ gw, const float* __restrict__ gb,
                                                 u16* __restrict__ lnout, float* __restrict__ shortcut,
                                                 const float* __restrict__ win, u16* __restrict__ wInB,
                                                 const float* __restrict__ wout, u16* __restrict__ wOutB,
                                                 const float* __restrict__ wprj, u16* __restrict__ wPrjB,
                                                 const float* __restrict__ xdw, u16* __restrict__ wXdB,
                                                 const float* __restrict__ wup, const float* __restrict__ lup,
                                                 const float* __restrict__ uup, const float* __restrict__ dco,
                                                 u16* __restrict__ wB) {
  const int id = blockIdx.x;
  const int t = threadIdx.x;
  if (id < 4096) {                       // -------- LayerNorm on token id --------
    const int tok = id;
    const float* xr = hs + (size_t)tok * DD;
    float v0 = xr[t], v1 = xr[t + 256], v2 = xr[t + 512];
    float s = v0 + v1 + v2;
    float q = v0 * v0 + v1 * v1 + v2 * v2;
#pragma unroll
    for (int off = 32; off > 0; off >>= 1) {
      s += __shfl_down(s, off, 64);
      q += __shfl_down(q, off, 64);
    }
    __shared__ float ss[4], qs[4];
    const int wid = t >> 6, lane = t & 63;
    if (lane == 0) { ss[wid] = s; qs[wid] = q; }
    __syncthreads();
    const float st = ss[0] + ss[1] + ss[2] + ss[3];
    const float qt = qs[0] + qs[1] + qs[2] + qs[3];
    const float mu = st * (1.f / 768.f);
    const float var = qt * (1.f / 768.f) - mu * mu;
    const float rstd = rsqrtf(var + 1e-5f);
    float* sc = shortcut + (size_t)tok * DD;
    u16* lo = lnout + (size_t)tok * DD;
    sc[t] = v0; sc[t + 256] = v1; sc[t + 512] = v2;
    lo[t]       = f2bf((v0 - mu) * rstd * gw[t] + gb[t]);
    lo[t + 256] = f2bf((v1 - mu) * rstd * gw[t + 256] + gb[t + 256]);
    lo[t + 512] = f2bf((v2 - mu) * rstd * gw[t + 512] + gb[t + 512]);
    return;
  }
  const int id2 = id - 4096;
  if (id2 < 6912) {                      // -------- 3 x 589824 f32 -> bf16 --------
    const int m = id2 / 2304;
    const int i = (id2 - m * 2304) * 256 + t;
    const float* s = (m == 0) ? win : (m == 1) ? wout : wprj;
    u16* d = (m == 0) ? wInB : (m == 1) ? wOutB : wPrjB;
    d[i] = f2bf(s[i]);
  } else if (id2 < 7104) {               // -------- xdown 48x768 -> 64x768 padded --------
    const int i = (id2 - 6912) * 256 + t;
    const int r = i / DD;
    wXdB[i] = (r < 48) ? f2bf(xdw[i]) : (u16)0;
  } else {                               // -------- gather scan weights --------
    const int c = id2 - 7104;
    u16* dst = wB + (size_t)c * 2048;
    for (int i = t; i < 2048; i += 256) {
      const int row = i >> 6, s = i & 63;
      u16 v = 0;
      if (row < 24 && s < 48) {
        const int k = row & 3, type = row >> 2;
        const int ch = k * DD + c;
        const float* src;
        if (type < 3) src = wup + ((size_t)(type * 3072 + ch)) * 48;
        else if (type == 3) src = lup + (size_t)ch * 48;
        else if (type == 4) src = uup + (size_t)ch * 48;
        else src = dco + (size_t)ch * 48;
        v = f2bf(src[s]);
      }
      dst[i] = v;
    }
  }
}

// ---------------- bf16 MFMA GEMM: out[o,pg] = sum_c A[o,c]*B[pg,c] ----------------
// BSRC 0: B token-major [pg][c].  BSRC 1: B channel-major [b][c][p] (LDS-transpose staging).
// mode 1: store f32 token-major out[pg*768 + o];  mode 3: store bf16 channel-major.
template <int BSRC>
__global__ __launch_bounds__(256) void gemm_bf16(const u16* __restrict__ A,
                                                 const u16* __restrict__ Bt,
                                                 void* __restrict__ outv, const int mode) {
  __shared__ u16 Al[64][40];
  __shared__ u16 BlF[144 * 40];   // row-permuted: phys = tok + (tok>>3)
  const int t = threadIdx.x;
  const int ntile = blockIdx.x * 128;
  const int mtile = blockIdx.y * 64;
  const int bb = ntile >> 10, pq0 = ntile & 1023;
  const int wid = t >> 6, lane = t & 63;
  const int m0 = (wid & 1) * 32, n0 = (wid >> 1) * 64;
  const int l15 = lane & 15, quad = lane >> 4;
  f32x4 acc[2][4];
#pragma unroll
  for (int mi = 0; mi < 2; ++mi)
#pragma unroll
    for (int ni = 0; ni < 4; ++ni) acc[mi][ni] = (f32x4){0.f, 0.f, 0.f, 0.f};
  const int ra = t >> 2, sa = t & 3;
  const u16* ag = A + (size_t)(mtile + ra) * DD + sa * 8;
  const int rb = t >> 1, hb = t & 1;                                   // BSRC 0 ids
  const u16* bg = Bt + (size_t)(ntile + rb) * DD + hb * 16;
  const int chp = t >> 4, tokg = t & 15, tok0 = tokg * 8;              // BSRC 1 ids
  const u16* bgc = Bt + ((size_t)(bb * DD + chp * 2)) * PP + pq0 + tok0;
  for (int k0 = 0; k0 < DD; k0 += 32) {
    const uint4 av = *reinterpret_cast<const uint4*>(ag + k0);
    uint4 bv0, bv1;
    if (BSRC == 0) {
      bv0 = *reinterpret_cast<const uint4*>(bg + k0);
      bv1 = *reinterpret_cast<const uint4*>(bg + k0 + 8);
    } else {
      bv0 = *reinterpret_cast<const uint4*>(bgc + (size_t)k0 * PP);
      bv1 = *reinterpret_cast<const uint4*>(bgc + (size_t)(k0 + 1) * PP);
    }
    __syncthreads();
    *reinterpret_cast<uint4*>(&Al[ra][sa * 8]) = av;
    if (BSRC == 0) {
      const int pr = rb + (rb >> 3);
      *reinterpret_cast<uint4*>(&BlF[pr * 40 + hb * 16]) = bv0;
      *reinterpret_cast<uint4*>(&BlF[pr * 40 + hb * 16 + 8]) = bv1;
    } else {
      union { uint4 v; u16 u[8]; } ua, ub;
      ua.v = bv0; ub.v = bv1;
#pragma unroll
      for (int i2 = 0; i2 < 8; ++i2) {
        const int tk = tok0 + i2;
        *reinterpret_cast<u32*>(&BlF[(tk + (tk >> 3)) * 40 + chp * 2]) =
            (u32)ua.u[i2] | ((u32)ub.u[i2] << 16);
      }
    }
    __syncthreads();
    short8v af[2];
#pragma unroll
    for (int mi = 0; mi < 2; ++mi)
      af[mi] = *reinterpret_cast<const short8v*>(&Al[m0 + mi * 16 + l15][quad * 8]);
    short8v bfr[4];
#pragma unroll
    for (int ni = 0; ni < 4; ++ni) {
      const int tl = n0 + ni * 16 + l15;
      bfr[ni] = *reinterpret_cast<const short8v*>(&BlF[(tl + (tl >> 3)) * 40 + quad * 8]);
    }
#pragma unroll
    for (int mi = 0; mi < 2; ++mi)
#pragma unroll
      for (int ni = 0; ni < 4; ++ni)
        acc[mi][ni] = __builtin_amdgcn_mfma_f32_16x16x32_bf16(af[mi], bfr[ni], acc[mi][ni], 0, 0, 0);
  }
#pragma unroll
  for (int mi = 0; mi < 2; ++mi) {
#pragma unroll
    for (int ni = 0; ni < 4; ++ni) {
      const int ob = mtile + m0 + mi * 16 + quad * 4;
      const int pg = ntile + n0 + ni * 16 + l15;
      if (mode == 1) {
        *reinterpret_cast<f32x4*>((float*)outv + (size_t)pg * DD + ob) = acc[mi][ni];
      } else {
        const int pq = pg & 1023;
        u16* dstb = (u16*)outv;
#pragma unroll
        for (int r = 0; r < 4; ++r)
          dstb[((size_t)(bb * DD + ob + r)) * PP + pq] = f2bf(acc[mi][ni][r]);
      }
    }
  }
}

// ---------------- xdown GEMM: xpA[(b*1024+i)*64 + coef] from channel-major y2 ----------------
// grid 256: 16-token N-tiles. A = wXdB 64x768 (rows 48+ zero), i = ((p&31)>>4)*512 + (p>>5)*16 + (p&15)
__global__ __launch_bounds__(256) void xdgemm_k(const u16* __restrict__ A,
                                                const u16* __restrict__ Ycm,
                                                u16* __restrict__ xpA) {
  __shared__ u16 Al[64][72];
  __shared__ u16 Bl[16][72];
  const int t = threadIdx.x;
  const int ntile = blockIdx.x * 16;
  const int bb = ntile >> 10, pq0 = ntile & 1023;
  const int wid = t >> 6, lane = t & 63, l15 = lane & 15, quad = lane >> 4;
  f32x4 acc = (f32x4){0.f, 0.f, 0.f, 0.f};
  const int arow = t >> 2, aks = (t & 3) * 16;
  const u16* ag = A + (size_t)arow * DD + aks;
  const int chp = t >> 3;          // 0..31 channel-pairs (ch = 2*chp)
  const int tk0 = (t & 7) * 2;     // tokens tk0, tk0+1
  const u16* bg0 = Ycm + ((size_t)(bb * DD + chp * 2)) * PP + pq0 + tk0;
  for (int k0 = 0; k0 < DD; k0 += 64) {
    const uint4 a0 = *reinterpret_cast<const uint4*>(ag + k0);
    const uint4 a1 = *reinterpret_cast<const uint4*>(ag + k0 + 8);
    const u32 b0 = *reinterpret_cast<const u32*>(bg0 + (size_t)k0 * PP);
    const u32 b1 = *reinterpret_cast<const u32*>(bg0 + (size_t)(k0 + 1) * PP);
    __syncthreads();
    *reinterpret_cast<uint4*>(&Al[arow][aks]) = a0;
    *reinterpret_cast<uint4*>(&Al[arow][aks + 8]) = a1;
    *reinterpret_cast<u32*>(&Bl[tk0][chp * 2]) = (b0 & 0xffffu) | (b1 << 16);
    *reinterpret_cast<u32*>(&Bl[tk0 + 1][chp * 2]) = (b0 >> 16) | (b1 & 0xffff0000u);
    __syncthreads();
#pragma unroll
    for (int ks = 0; ks < 2; ++ks) {
      const short8v af = *reinterpret_cast<const short8v*>(&Al[wid * 16 + l15][ks * 32 + quad * 8]);
      const short8v bf = *reinterpret_cast<const short8v*>(&Bl[l15][ks * 32 + quad * 8]);
      acc = __builtin_amdgcn_mfma_f32_16x16x32_bf16(af, bf, acc, 0, 0, 0);
    }
  }
  const int pq = pq0 + l15;
  const int i = ((pq & 31) >> 4) * 512 + (pq >> 5) * 16 + (pq & 15);
  u16* dst = xpA + ((size_t)(bb * 1024 + i)) * 64 + wid * 16 + quad * 4;
  *reinterpret_cast<uint2*>(dst) = make_uint2(pk_trunc(acc[1], acc[0]), pk_trunc(acc[3], acc[2]));
}

// ---------------- depthwise 7x7 + bias, bf16 -> bf16 ----------------
__global__ __launch_bounds__(256) void dwconv7_k(const u16* __restrict__ x,
                                                 const float* __restrict__ wgt,
                                                 const float* __restrict__ bias,
                                                 u16* __restrict__ y) {
  const int bc = blockIdx.x;
  const int c = bc % DD;
  __shared__ float tile[38 * 38];
  __shared__ float wl[49];
  __shared__ float bsh[1];
  const int t = threadIdx.x;
  for (int i = t; i < 38 * 38; i += 256) tile[i] = 0.f;
  __syncthreads();
  const u16* xr = x + (size_t)bc * PP;
  for (int i = t; i < 512; i += 256) {
    const u32 v = reinterpret_cast<const u32*>(xr)[i];
    const int p0 = i * 2;
    const int h = p0 >> 5, w = p0 & 31;
    tile[(h + 3) * 38 + w + 3] = b2f((u16)v);
    tile[(h + 3) * 38 + w + 4] = b2f((u16)(v >> 16));
  }
  if (t < 49) wl[t] = wgt[c * 49 + t];
  if (t == 0) bsh[0] = bias[c];
  __syncthreads();
  u16* yo = y + (size_t)bc * PP;
  for (int i = t; i < 1024; i += 256) {
    const int h = i >> 5, w = i & 31;
    float acc = bsh[0];
#pragma unroll
    for (int kh = 0; kh < 7; ++kh)
#pragma unroll
      for (int kw = 0; kw < 7; ++kw)
        acc = fmaf(wl[kh * 7 + kw], tile[(h + kh) * 38 + (w + kw)], acc);
    yo[i] = f2bf(acc);
  }
}

// ---------------- depthwise 3x3 (no bias) + x*relu(x), bf16 -> bf16 ----------------
__global__ __launch_bounds__(256) void dwconv3_k(const u16* __restrict__ x,
                                                 const float* __restrict__ wgt,
                                                 u16* __restrict__ y) {
  const int bc = blockIdx.x;
  const int c = bc % DD;
  __shared__ float tile[34 * 34];
  __shared__ float wl[9];
  const int t = threadIdx.x;
  for (int i = t; i < 34 * 34; i += 256) tile[i] = 0.f;
  __syncthreads();
  const u16* xr = x + (size_t)bc * PP;
  for (int i = t; i < 512; i += 256) {
    const u32 v = reinterpret_cast<const u32*>(xr)[i];
    const int p0 = i * 2;
    const int h = p0 >> 5, w = p0 & 31;
    tile[(h + 1) * 34 + w + 1] = b2f((u16)v);
    tile[(h + 1) * 34 + w + 2] = b2f((u16)(v >> 16));
  }
  if (t < 9) wl[t] = wgt[c * 9 + t];
  __syncthreads();
  u16* yo = y + (size_t)bc * PP;
  for (int i = t; i < 1024; i += 256) {
    const int h = i >> 5, w = i & 31;
    float acc = 0.f;
#pragma unroll
    for (int kh = 0; kh < 3; ++kh)
#pragma unroll
      for (int kw = 0; kw < 3; ++kw)
        acc = fmaf(wl[kh * 3 + kw], tile[(h + kh) * 34 + (w + kw)], acc);
    const float r = acc > 0.f ? acc * acc : 0.f;
    yo[i] = f2bf(r);
  }
}

// ---------------- fused MFMA projections + 4-direction chunked scan + recombine ----------------
// grid = 6144: blockIdx.x = bc*2 + half. Phase B neighbor exchange via DPP (VALU pipe);
// prow via one ds_read_b128 (stride-40 planes, 16B-aligned windows).
__global__ __launch_bounds__(256, 5) void scan_k(const u16* __restrict__ y2b,
                                                 const u16* __restrict__ xpA,
                                                 const u16* __restrict__ wB,
                                                 const float* __restrict__ mwp,
                                                 u16* __restrict__ out1) {
  const int bid = blockIdx.x;
  const int bc = bid >> 1;
  const int half = bid & 1;
  const int b = bc / DD;
  const int c = bc - b * DD;
  __shared__ u16 act[24 * ASN];       // 24,960 B
  __shared__ u16 planeb[32][40];      //  2,560 B  planeb[h][w] = x(h,w)
  __shared__ u16 planeTb[32][40];     //  2,560 B  planeTb[h][w] = x(w,h)
  __shared__ u16 outpb[2][16][34];    //  2,176 B   (total 32,256)
  const int t = threadIdx.x;
  const int wid = t >> 6, lane = t & 63, l15 = lane & 15, quad = lane >> 4;
  {
    const u16* yp = y2b + (size_t)bc * PP;
    for (int i = t; i < 512; i += 256) {
      const u32 v = reinterpret_cast<const u32*>(yp)[i];
      const int p0 = i * 2;
      const int hh = p0 >> 5, ww = p0 & 31;
      *reinterpret_cast<u32*>(&planeb[hh][ww]) = v;
      planeTb[ww][hh] = (u16)v;
      planeTb[ww + 1][hh] = (u16)(v >> 16);
    }
  }
  // ---- phase A: projections via MFMA (512 i-rows, 128 per wave) ----
  {
    const u16* wc = wB + (size_t)c * 2048;
    short8v bw[2][2];
#pragma unroll
    for (int nt = 0; nt < 2; ++nt)
#pragma unroll
      for (int ks = 0; ks < 2; ++ks)
        bw[nt][ks] = *reinterpret_cast<const short8v*>(wc + (nt * 16 + l15) * 64 + ks * 32 + quad * 8);
    const u16* ab = xpA + ((size_t)(b * 1024 + half * 512 + wid * 128)) * 64;
#pragma unroll 4
    for (int mt = 0; mt < 8; ++mt) {
      const u16* ar = ab + (mt * 16 + l15) * 64 + quad * 8;
      const short8v a0 = *reinterpret_cast<const short8v*>(ar);
      const short8v a1 = *reinterpret_cast<const short8v*>(ar + 32);
      f32x4 acc0 = {0.f, 0.f, 0.f, 0.f}, acc1 = {0.f, 0.f, 0.f, 0.f};
      acc0 = __builtin_amdgcn_mfma_f32_16x16x32_bf16(a0, bw[0][0], acc0, 0, 0, 0);
      acc0 = __builtin_amdgcn_mfma_f32_16x16x32_bf16(a1, bw[0][1], acc0, 0, 0, 0);
      acc1 = __builtin_amdgcn_mfma_f32_16x16x32_bf16(a0, bw[1][0], acc1, 0, 0, 0);
      acc1 = __builtin_amdgcn_mfma_f32_16x16x32_bf16(a1, bw[1][1], acc1, 0, 0, 0);
      const int qb = wid * 128 + mt * 16 + quad * 4;
      *reinterpret_cast<uint2*>(&act[l15 * ASN + qb]) =
          make_uint2(pk_trunc(acc0[1], acc0[0]), pk_trunc(acc0[3], acc0[2]));
      if (l15 < 8)
        *reinterpret_cast<uint2*>(&act[(16 + l15) * ASN + qb]) =
            make_uint2(pk_trunc(acc1[1], acc1[0]), pk_trunc(acc1[3], acc1[2]));
    }
  }
  __syncthreads();
  // ---- phase B: chunked scan, one direction per lane ----
  const int dpair = wid & 1;
  const int ncl = wid >> 1;
  const int d = lane >> 5;
  const int h = lane & 31;
  const int k = dpair * 2 + d;
  const float mw = mwp[k];
  const int base16 = h * 16 + ncl * 8;
  const short8v vGl = *reinterpret_cast<const short8v*>(&act[(0  + k) * ASN + base16]);
  const short8v vGm = *reinterpret_cast<const short8v*>(&act[(4  + k) * ASN + base16]);
  const short8v vGr = *reinterpret_cast<const short8v*>(&act[(8  + k) * ASN + base16]);
  const short8v vL  = *reinterpret_cast<const short8v*>(&act[(12 + k) * ASN + base16]);
  const short8v vU  = *reinterpret_cast<const short8v*>(&act[(16 + k) * ASN + base16]);
  const short8v vD  = *reinterpret_cast<const short8v*>(&act[(20 + k) * ASN + base16]);
  // one b128 read covers the lane's 8 x-values (reversed window for dpair=1)
  const int wst = dpair ? (24 - half * 16 - ncl * 8) : (half * 16 + ncl * 8);
  const u16* prowp = (d == 0) ? &planeb[h][wst] : &planeTb[h][wst];
  const short8v vP = *reinterpret_cast<const short8v*>(prowp);
  const bool top = (h == 0), bot = (h == 31);
  float gl[8], gm[8], gr[8], Lx[8], xvv[8];
#pragma unroll
  for (int j = 0; j < 8; ++j) {
    const float xv = ex8(vP, dpair ? (7 - j) : j);
    float el = __expf(-ex8(vGl, j));
    const float em = __expf(-ex8(vGm, j));
    float er = __expf(-ex8(vGr, j));
    if (top) el = 1e30f;
    if (bot) er = 1e30f;
    const float pl = 1.f + el, pm = 1.f + em, pr = 1.f + er;
    const float ul = pm * pr, um = pl * pr, ur = pl * pm;
    const float rcpS = __builtin_amdgcn_rcpf(ul + um + ur);
    gl[j] = ul * rcpS; gm[j] = um * rcpS; gr[j] = ur * rcpS;
    Lx[j] = ex8(vL, j) * xv;
    xvv[j] = xv;
  }
  // tight serial pass: neighbor exchange on the VALU pipe via DPP
  float H = 0.f;
#pragma unroll
  for (int j = 0; j < 8; ++j) {
    const int Hb = __builtin_bit_cast(int, H);
    const float up = __builtin_bit_cast(float,
        __builtin_amdgcn_update_dpp(0, Hb, 0x138, 0xf, 0xf, true));  // wave_shr:1  lane i <- i-1
    const float dn = __builtin_bit_cast(float,
        __builtin_amdgcn_update_dpp(0, Hb, 0x130, 0xf, 0xf, true));  // wave_shl:1  lane i <- i+1
    H = fmaf(gl[j], up, fmaf(gm[j], H, fmaf(gr[j], dn, Lx[j])));
    float part = fmaf(H, ex8(vU, j), xvv[j] * ex8(vD, j)) * mw;
    part += __shfl_xor(part, 32, 64);
    if (d == 0)
      outpb[dpair][ncl * 8 + j][h] = (u16)(__builtin_bit_cast(u32, part) >> 16);
  }
  __syncthreads();
  const int hh = t >> 3, wp = t & 7;
  const float v0 = b2f(outpb[0][wp * 2][hh]) + b2f(outpb[1][wp * 2][hh]);
  const float v1 = b2f(outpb[0][wp * 2 + 1][hh]) + b2f(outpb[1][wp * 2 + 1][hh]);
  const u32 pk = pk_trunc(v1, v0);
  *reinterpret_cast<u32*>(out1 + (size_t)bc * PP + hh * 32 + half * 16 + wp * 2) = pk;
}

extern "C" void kernel_launch(void* const* d_in, const int* in_sizes, int n_in,
                              void* d_out, int out_size, void* d_ws, size_t ws_size,
                              hipStream_t stream) {
  const float* hs   = (const float*)d_in[0];
  const float* nw   = (const float*)d_in[1];
  const float* nb   = (const float*)d_in[2];
  const float* win  = (const float*)d_in[3];
  const float* c7w  = (const float*)d_in[4];
  const float* c7b  = (const float*)d_in[5];
  const float* xdw  = (const float*)d_in[6];
  const float* wupw = (const float*)d_in[7];
  const float* lupw = (const float*)d_in[8];
  const float* uupw = (const float*)d_in[9];
  const float* dcow = (const float*)d_in[10];
  const float* mww  = (const float*)d_in[11];
  const float* wout = (const float*)d_in[12];
  const float* odw  = (const float*)d_in[13];
  const float* wprj = (const float*)d_in[14];
  float* out0 = (float*)d_out;
  float* shortcut = out0 + (size_t)NTOK * DD;

  char* ws = (char*)d_ws;
  u16* lnA    = (u16*)(ws + 0);            // 6,291,456
  u16* wInB   = (u16*)(ws + 6291456);      // 1,179,648
  u16* wOutB  = (u16*)(ws + 7471104);      // 1,179,648
  u16* wPrjB  = (u16*)(ws + 8650752);      // 1,179,648
  u16* wB     = (u16*)(ws + 9830400);      // 3,145,728
  u16* wXdB   = (u16*)(ws + 12976128);     //    98,304
  u16* xpA    = (u16*)(ws + 13074432);     //   524,288
  u16* y1b    = (u16*)(ws + 13598720);     // 6,291,456  y1 (gemm1->dw7); later y3 (gemm2->dw3)
  u16* y2b    = (u16*)(ws + 19890176);     // 6,291,456  y2 (dw7 -> xdgemm+scan)
  u16* out1   = (u16*)(ws + 26181632);     // 6,291,456  scan->gemm2; later y4 (dw3->gemm3)
  u16* y3b    = y1b;
  u16* y4b    = out1;

  prep_ln_k<<<11968, 256, 0, stream>>>(hs, nw, nb, lnA, shortcut,
                                       win, wInB, wout, wOutB, wprj, wPrjB,
                                       xdw, wXdB, wupw, lupw, uupw, dcow, wB);
  gemm_bf16<0><<<dim3(32, 12), 256, 0, stream>>>(wInB, lnA, y1b, 3);       // in_proj -> y1 bf16 ch-major
  dwconv7_k<<<3072, 256, 0, stream>>>(y1b, c7w, c7b, y2b);                 // y2 bf16 ch-major
  xdgemm_k<<<256, 256, 0, stream>>>(wXdB, y2b, xpA);                       // xdown -> xpA (h-major rows)
  scan_k<<<6144, 256, 0, stream>>>(y2b, xpA, wB, mww, out1);               // out1 bf16 ch-major
  gemm_bf16<1><<<dim3(32, 12), 256, 0, stream>>>(wOutB, out1, y3b, 3);     // outconv -> y3 bf16 ch-major
  dwconv3_k<<<3072, 256, 0, stream>>>(y3b, odw, y4b);                      // dw3 + x*relu(x) -> y4 ch-major
  gemm_bf16<1><<<dim3(32, 12), 256, 0, stream>>>(wPrjB, y4b, out0, 1);     // outproj -> out f32 [b][t][d]
}